// Round 1
// baseline (557.535 us; speedup 1.0000x reference)
//
#include <hip/hip_runtime.h>
#include <math.h>

#define BB 16
#define MM 32
#define NN 8400
#define NCC 80
#define RMM 16
#define EPSF 1e-7f

// ---------------------------------------------------------------------------
// ws layout (floats):
//   pdbox : 2*BB*NN*4
//   lse   : 2*BB*NN*4
//   align : 2*BB*MM*NN
//   topk1 : BB*MM*10 (int)
//   topk2 : BB*MM    (int)
//   tgi   : 2*BB*NN  (int)
//   mpos  : 2*BB*NN
//   acc   : 16   (acc[br*8+q]: q0=sum_xt q1=sum_box q2=sum_dfl q3=n_fg q4=sum_mpos q5=sum_softplus)
// ---------------------------------------------------------------------------

__global__ __launch_bounds__(64) void zero_acc_kernel(float* acc) {
    if (threadIdx.x < 16) acc[threadIdx.x] = 0.0f;
}

// ---- kernel 1: decode bboxes + per-side logsumexp --------------------------
__global__ __launch_bounds__(256) void decode_kernel(
    const float* __restrict__ regs0, const float* __restrict__ regs1,
    const float* __restrict__ anchors, const float* __restrict__ strides,
    float* __restrict__ pdbox, float* __restrict__ lse)
{
    int i = blockIdx.x * 256 + threadIdx.x;
    if (i >= 2 * BB * NN) return;
    int br = i / (BB * NN);
    int bn = i - br * (BB * NN);
    int n = bn % NN;
    const float* regs = (br == 0 ? regs0 : regs1) + (size_t)bn * (4 * RMM);
    const float4* p4 = (const float4*)regs;

    float d[4], l[4];
#pragma unroll
    for (int s = 0; s < 4; ++s) {
        float4 a0 = p4[s * 4 + 0];
        float4 a1 = p4[s * 4 + 1];
        float4 a2 = p4[s * 4 + 2];
        float4 a3 = p4[s * 4 + 3];
        float xs[16] = {a0.x, a0.y, a0.z, a0.w, a1.x, a1.y, a1.z, a1.w,
                        a2.x, a2.y, a2.z, a2.w, a3.x, a3.y, a3.z, a3.w};
        float mx = xs[0];
#pragma unroll
        for (int j = 1; j < 16; ++j) mx = fmaxf(mx, xs[j]);
        float se = 0.0f, sd = 0.0f;
#pragma unroll
        for (int j = 0; j < 16; ++j) {
            float e = expf(xs[j] - mx);
            se += e;
            sd += e * (float)j;
        }
        d[s] = sd / se;
        l[s] = mx + logf(se);
    }
    float ax = anchors[2 * n], ay = anchors[2 * n + 1];
    float st = strides[n];
    float4 box;
    box.x = ax - d[0] * st;
    box.y = ay - d[1] * st;
    box.z = ax + d[2] * st;
    box.w = ay + d[3] * st;
    ((float4*)pdbox)[i] = box;
    float4 lv = make_float4(l[0], l[1], l[2], l[3]);
    ((float4*)lse)[i] = lv;
}

// ---- kernel 2: align metric (B,M,N) per branch -----------------------------
__global__ __launch_bounds__(256) void align_kernel(
    const float* __restrict__ cls0, const float* __restrict__ cls1,
    const float* __restrict__ anchors,
    const int* __restrict__ gt_labels, const float* __restrict__ gt_bboxes,
    const float* __restrict__ pdbox, float* __restrict__ alignw)
{
    int n = blockIdx.x * 256 + threadIdx.x;
    int r = blockIdx.y;                 // 0 .. 2*BB*MM-1
    if (n >= NN) return;
    int br = r / (BB * MM);
    int bm = r - br * (BB * MM);
    int b = bm / MM;

    const float* gt = gt_bboxes + (size_t)bm * 4;
    float g0 = gt[0], g1 = gt[1], g2 = gt[2], g3 = gt[3];
    int lab = gt_labels[bm];

    float4 pb = ((const float4*)pdbox)[(size_t)(br * BB + b) * NN + n];
    float iw = fmaxf(fminf(pb.z, g2) - fmaxf(pb.x, g0), 0.0f);
    float ih = fmaxf(fminf(pb.w, g3) - fmaxf(pb.y, g1), 0.0f);
    float inter = iw * ih;
    float pa = (pb.z - pb.x) * (pb.w - pb.y);
    float ga = (g2 - g0) * (g3 - g1);
    float iou = inter / (pa + ga - inter + EPSF);

    float ax = anchors[2 * n], ay = anchors[2 * n + 1];
    float ing = (ax >= g0 && ax <= g2 && ay >= g1 && ay <= g3) ? 1.0f : 0.0f;

    const float* cls = (br == 0 ? cls0 : cls1);
    float x = cls[((size_t)b * NN + n) * NCC + lab];
    float sig = 1.0f / (1.0f + expf(-x));

    float al = sig * powf(iou, 6.0f) * ing;
    alignw[(size_t)r * NN + n] = al;
}

// ---- kernel 3: stable top-k per (branch,b,m) row ---------------------------
__global__ __launch_bounds__(256) void topk_kernel(
    const float* __restrict__ alignw, int* __restrict__ topk1, int* __restrict__ topk2)
{
    int r = blockIdx.x;                 // 0 .. 2*BB*MM-1
    int br = r / (BB * MM);
    int bm = r - br * (BB * MM);
    int k = (br == 0) ? 10 : 1;
    int* outp = (br == 0) ? (topk1 + bm * 10) : (topk2 + bm);
    const float* row = alignw + (size_t)r * NN;

    __shared__ float sval[256];
    __shared__ int sidx[256];
    __shared__ int sel[10];
    int tid = threadIdx.x;

    for (int p = 0; p < k; ++p) {
        float bv = -1.0f;
        int bi = NN;
        for (int n = tid; n < NN; n += 256) {
            bool skip = false;
            for (int j = 0; j < p; ++j)
                if (sel[j] == n) skip = true;
            if (skip) continue;
            float v = row[n];
            if (v > bv || (v == bv && n < bi)) { bv = v; bi = n; }
        }
        sval[tid] = bv;
        sidx[tid] = bi;
        __syncthreads();
        for (int sft = 128; sft > 0; sft >>= 1) {
            if (tid < sft) {
                float ov = sval[tid + sft];
                int oi = sidx[tid + sft];
                if (ov > sval[tid] || (ov == sval[tid] && oi < sidx[tid])) {
                    sval[tid] = ov;
                    sidx[tid] = oi;
                }
            }
            __syncthreads();
        }
        if (tid == 0) {
            sel[p] = sidx[0];
            outp[p] = sidx[0];
        }
        __syncthreads();
    }
}

// ---- kernel 4: per-anchor assignment ---------------------------------------
__global__ __launch_bounds__(256) void assign_kernel(
    const float* __restrict__ alignw, const int* __restrict__ topk1,
    const int* __restrict__ topk2, const float* __restrict__ mask_gt,
    int* __restrict__ tgi, float* __restrict__ mposw)
{
    int i = blockIdx.x * 256 + threadIdx.x;
    if (i >= 2 * BB * NN) return;
    int br = i / (BB * NN);
    int bn = i - br * (BB * NN);
    int b = bn / NN;
    int n = bn - b * NN;

    const float* col = alignw + ((size_t)(br * BB + b) * MM) * NN + n;
    float best = col[0];
    int mi = 0;
    for (int m = 1; m < MM; ++m) {
        float v = col[(size_t)m * NN];
        if (v > best) { best = v; mi = m; }
    }
    int ind = 0;
    if (br == 0) {
        const int* tk = topk1 + (b * MM + mi) * 10;
        for (int j = 0; j < 10; ++j)
            if (tk[j] == n) ind = 1;
    } else {
        if (topk2[b * MM + mi] == n) ind = 1;
    }
    float tm = ind ? mask_gt[b * MM + mi] : 0.0f;
    tgi[i] = (tm > 0.0f) ? mi : 0;
    mposw[i] = tm;
}

// ---- block reduce helper ---------------------------------------------------
__device__ inline float blockReduceSum(float v, float* sh) {
    for (int o = 32; o > 0; o >>= 1) v += __shfl_down(v, o, 64);
    int lane = threadIdx.x & 63;
    int w = threadIdx.x >> 6;
    __syncthreads();
    if (lane == 0) sh[w] = v;
    __syncthreads();
    float r = 0.0f;
    if (threadIdx.x == 0) r = sh[0] + sh[1] + sh[2] + sh[3];
    return r;
}

// ---- kernel 5a: sum of softplus over all cls scores (one branch) -----------
__global__ __launch_bounds__(256) void softplus_kernel(
    const float* __restrict__ cls, float* __restrict__ acc_slot)
{
    size_t total4 = (size_t)BB * NN * NCC / 4;
    float s = 0.0f;
    for (size_t i = (size_t)blockIdx.x * 256 + threadIdx.x; i < total4;
         i += (size_t)gridDim.x * 256) {
        float4 v = ((const float4*)cls)[i];
        s += fmaxf(v.x, 0.0f) + log1pf(expf(-fabsf(v.x)));
        s += fmaxf(v.y, 0.0f) + log1pf(expf(-fabsf(v.y)));
        s += fmaxf(v.z, 0.0f) + log1pf(expf(-fabsf(v.z)));
        s += fmaxf(v.w, 0.0f) + log1pf(expf(-fabsf(v.w)));
    }
    __shared__ float sh[4];
    float r = blockReduceSum(s, sh);
    if (threadIdx.x == 0) atomicAdd(acc_slot, r);
}

// ---- kernel 5b: assignment-dependent loss terms ----------------------------
__global__ __launch_bounds__(256) void loss_kernel(
    const float* __restrict__ cls0, const float* __restrict__ cls1,
    const float* __restrict__ regs0, const float* __restrict__ regs1,
    const float* __restrict__ anchors, const float* __restrict__ strides,
    const int* __restrict__ gt_labels, const float* __restrict__ gt_bboxes,
    const float* __restrict__ pdbox, const float* __restrict__ lse,
    const int* __restrict__ tgi, const float* __restrict__ mposw,
    float* __restrict__ acc)
{
    int i = blockIdx.x * 256 + threadIdx.x;
    int br0 = (blockIdx.x * 256) / (BB * NN);   // whole block is in one branch

    float sxt = 0.0f, sbox = 0.0f, sdfl = 0.0f, sfg = 0.0f, smp = 0.0f;
    if (i < 2 * BB * NN) {
        int br = i / (BB * NN);
        int bn = i - br * (BB * NN);
        int b = bn / NN;
        int n = bn - b * NN;
        float mp = mposw[i];
        smp = mp;
        if (mp > 0.0f) {
            sfg = 1.0f;
            int gi = tgi[i];
            const float* gt = gt_bboxes + (size_t)(b * MM + gi) * 4;
            float t0 = gt[0] * mp, t1 = gt[1] * mp, t2 = gt[2] * mp, t3 = gt[3] * mp;
            float4 pb = ((const float4*)pdbox)[i];

            // plain IoU (for tscores)
            float iw = fmaxf(fminf(pb.z, t2) - fmaxf(pb.x, t0), 0.0f);
            float ih = fmaxf(fminf(pb.w, t3) - fmaxf(pb.y, t1), 0.0f);
            float inter = iw * ih;
            float w1 = pb.z - pb.x, h1 = pb.w - pb.y;
            float w2 = t2 - t0, h2 = t3 - t1;
            float uni = w1 * h1 + w2 * h2 - inter + EPSF;
            float iou = inter / uni;

            // -x*t term of BCE
            int lab = gt_labels[b * MM + gi];
            const float* cls = (br == 0 ? cls0 : cls1);
            float x = cls[((size_t)b * NN + n) * NCC + lab];
            sxt = x * iou;

            // CIoU (replicating reference's ch bug: ch = max(y2) - b1y1)
            float cw = fmaxf(pb.z, t2) - fminf(pb.x, t0);
            float ch = fmaxf(pb.w, t3) - pb.y;     // BUG in reference, replicated
            float c2 = cw * cw + ch * ch + EPSF;
            float dx = pb.x + pb.z - t0 - t2;
            float dy = pb.y + pb.w - t1 - t3;
            float rho2 = (dx * dx + dy * dy) * 0.25f;
            float dat = atanf(w2 / (h2 + EPSF)) - atanf(w1 / (h1 + EPSF));
            float v = 0.40528473f * dat * dat;     // 4/pi^2
            float alpha_ = v / (v - iou + 1.0000001f);
            float ciou = iou - (rho2 / c2 + v * alpha_);
            sbox = 1.0f - ciou;

            // DFL
            float st = strides[n];
            float ax = anchors[2 * n], ay = anchors[2 * n + 1];
            float tb[4] = {(ax - t0) / st, (ay - t1) / st,
                           (t2 - ax) / st, (t3 - ay) / st};
            float4 l4 = ((const float4*)lse)[i];
            float lv[4] = {l4.x, l4.y, l4.z, l4.w};
            const float* regs = (br == 0 ? regs1 - regs1 + regs0 : regs1) + (size_t)bn * 64;
            float dsum = 0.0f;
#pragma unroll
            for (int s2 = 0; s2 < 4; ++s2) {
                float t = fminf(fmaxf(tb[s2], 0.0f), (float)RMM - 1.01f);
                int tl = (int)t;
                float wl = (float)(tl + 1) - t;
                float wr = 1.0f - wl;
                float lp_l = regs[s2 * 16 + tl] - lv[s2];
                float lp_r = regs[s2 * 16 + tl + 1] - lv[s2];
                dsum += -(lp_l * wl + lp_r * wr);
            }
            sdfl = dsum;
        }
    }

    __shared__ float sh[4];
    float vals[5] = {sxt, sbox, sdfl, sfg, smp};
#pragma unroll
    for (int q = 0; q < 5; ++q) {
        float r = blockReduceSum(vals[q], sh);
        if (threadIdx.x == 0) atomicAdd(&acc[br0 * 8 + q], r);
    }
}

// ---- kernel 6: finalize ----------------------------------------------------
__global__ __launch_bounds__(64) void finalize_kernel(
    const float* __restrict__ acc, float* __restrict__ out)
{
    if (threadIdx.x == 0 && blockIdx.x == 0) {
        float t[2], c[2], bx[2], df[2];
        for (int br = 0; br < 2; ++br) {
            const float* a = acc + br * 8;
            float nfg = fmaxf(a[3], 1.0f);
            float lcls = (a[5] - a[0]) / fmaxf(a[4], 1.0f);
            float lbox = a[1] / nfg;
            float ldfl = a[2] / (nfg * 4.0f);
            t[br] = lcls * 1.0f + lbox * 7.5f + ldfl * 1.5f;
            c[br] = lcls;
            bx[br] = lbox;
            df[br] = ldfl;
        }
        out[0] = t[0] + t[1];
        out[1] = c[0] + c[1];
        out[2] = bx[0] + bx[1];
        out[3] = df[0] + df[1];
        out[4] = t[0];
        out[5] = t[1];
    }
}

// ---------------------------------------------------------------------------
extern "C" void kernel_launch(void* const* d_in, const int* in_sizes, int n_in,
                              void* d_out, int out_size, void* d_ws, size_t ws_size,
                              hipStream_t stream) {
    const float* cls0    = (const float*)d_in[0];  // cls_scores
    const float* regs0   = (const float*)d_in[1];  // box_regs
    const float* cls1    = (const float*)d_in[2];  // one2one_cls
    const float* regs1   = (const float*)d_in[3];  // one2one_reg
    const float* anchors = (const float*)d_in[4];
    const float* strides = (const float*)d_in[5];
    const int*   gt_labels = (const int*)d_in[6];
    const float* gt_bboxes = (const float*)d_in[7];
    const float* mask_gt   = (const float*)d_in[8];
    float* out = (float*)d_out;

    float* pdbox  = (float*)d_ws;                       // 2*BB*NN*4
    float* lse    = pdbox + (size_t)2 * BB * NN * 4;    // 2*BB*NN*4
    float* alignw = lse + (size_t)2 * BB * NN * 4;      // 2*BB*MM*NN
    int*   topk1  = (int*)(alignw + (size_t)2 * BB * MM * NN);  // BB*MM*10
    int*   topk2  = topk1 + BB * MM * 10;               // BB*MM
    int*   tgiw   = topk2 + BB * MM;                    // 2*BB*NN
    float* mposw  = (float*)(tgiw + 2 * BB * NN);       // 2*BB*NN
    float* acc    = mposw + 2 * BB * NN;                // 16

    zero_acc_kernel<<<1, 64, 0, stream>>>(acc);

    int total = 2 * BB * NN;           // 268800
    int blocks = (total + 255) / 256;  // 1050

    decode_kernel<<<blocks, 256, 0, stream>>>(regs0, regs1, anchors, strides, pdbox, lse);

    dim3 agrid((NN + 255) / 256, 2 * BB * MM);
    align_kernel<<<agrid, 256, 0, stream>>>(cls0, cls1, anchors, gt_labels, gt_bboxes,
                                            pdbox, alignw);

    topk_kernel<<<2 * BB * MM, 256, 0, stream>>>(alignw, topk1, topk2);

    assign_kernel<<<blocks, 256, 0, stream>>>(alignw, topk1, topk2, mask_gt, tgiw, mposw);

    softplus_kernel<<<2048, 256, 0, stream>>>(cls0, &acc[0 * 8 + 5]);
    softplus_kernel<<<2048, 256, 0, stream>>>(cls1, &acc[1 * 8 + 5]);

    loss_kernel<<<blocks, 256, 0, stream>>>(cls0, cls1, regs0, regs1, anchors, strides,
                                            gt_labels, gt_bboxes, pdbox, lse,
                                            tgiw, mposw, acc);

    finalize_kernel<<<1, 64, 0, stream>>>(acc, out);
}

// Round 2
// 349.197 us; speedup vs baseline: 1.5966x; 1.5966x over previous
//
#include <hip/hip_runtime.h>
#include <math.h>

#define BB 16
#define MM 32
#define NN 8400
#define NCC 80
#define RMM 16
#define EPSF 1e-7f

// ---------------------------------------------------------------------------
// ws layout (floats):
//   pdbox : 2*BB*NN*4
//   lse   : 2*BB*NN*4
//   align : 2*BB*MM*NN
//   topk1 : BB*MM*10 (int)
//   topk2 : BB*MM    (int)
//   tgi   : 2*BB*NN  (int)
//   mpos  : 2*BB*NN
//   acc   : 16   (acc[br*8+q]: q0=sum_xt q1=sum_box q2=sum_dfl q3=n_fg q4=sum_mpos q5=sum_softplus)
// ---------------------------------------------------------------------------

__global__ __launch_bounds__(64) void zero_acc_kernel(float* acc) {
    if (threadIdx.x < 16) acc[threadIdx.x] = 0.0f;
}

// ---- kernel 1: decode bboxes + per-side logsumexp --------------------------
__global__ __launch_bounds__(256) void decode_kernel(
    const float* __restrict__ regs0, const float* __restrict__ regs1,
    const float* __restrict__ anchors, const float* __restrict__ strides,
    float* __restrict__ pdbox, float* __restrict__ lse)
{
    int i = blockIdx.x * 256 + threadIdx.x;
    if (i >= 2 * BB * NN) return;
    int br = i / (BB * NN);
    int bn = i - br * (BB * NN);
    int n = bn % NN;
    const float* regs = (br == 0 ? regs0 : regs1) + (size_t)bn * (4 * RMM);
    const float4* p4 = (const float4*)regs;

    float d[4], l[4];
#pragma unroll
    for (int s = 0; s < 4; ++s) {
        float4 a0 = p4[s * 4 + 0];
        float4 a1 = p4[s * 4 + 1];
        float4 a2 = p4[s * 4 + 2];
        float4 a3 = p4[s * 4 + 3];
        float xs[16] = {a0.x, a0.y, a0.z, a0.w, a1.x, a1.y, a1.z, a1.w,
                        a2.x, a2.y, a2.z, a2.w, a3.x, a3.y, a3.z, a3.w};
        float mx = xs[0];
#pragma unroll
        for (int j = 1; j < 16; ++j) mx = fmaxf(mx, xs[j]);
        float se = 0.0f, sd = 0.0f;
#pragma unroll
        for (int j = 0; j < 16; ++j) {
            float e = expf(xs[j] - mx);
            se += e;
            sd += e * (float)j;
        }
        d[s] = sd / se;
        l[s] = mx + logf(se);
    }
    float ax = anchors[2 * n], ay = anchors[2 * n + 1];
    float st = strides[n];
    float4 box;
    box.x = ax - d[0] * st;
    box.y = ay - d[1] * st;
    box.z = ax + d[2] * st;
    box.w = ay + d[3] * st;
    ((float4*)pdbox)[i] = box;
    float4 lv = make_float4(l[0], l[1], l[2], l[3]);
    ((float4*)lse)[i] = lv;
}

// ---- kernel 2: align metric (B,M,N), one block covers all M for an n-chunk -
__global__ __launch_bounds__(256) void align_kernel(
    const float* __restrict__ cls0, const float* __restrict__ cls1,
    const float* __restrict__ anchors,
    const int* __restrict__ gt_labels, const float* __restrict__ gt_bboxes,
    const float* __restrict__ pdbox, float* __restrict__ alignw)
{
    int n = blockIdx.x * 256 + threadIdx.x;
    int rb = blockIdx.y;                 // 0 .. 2*BB-1  (branch*BB + b)
    int br = rb / BB;
    int b = rb - br * BB;

    __shared__ float g[MM * 4];
    __shared__ int gl[MM];
    if (threadIdx.x < MM * 4) g[threadIdx.x] = gt_bboxes[b * MM * 4 + threadIdx.x];
    if (threadIdx.x < MM) gl[threadIdx.x] = gt_labels[b * MM + threadIdx.x];
    __syncthreads();
    if (n >= NN) return;

    float4 pb = ((const float4*)pdbox)[(size_t)rb * NN + n];
    float ax = anchors[2 * n], ay = anchors[2 * n + 1];
    float pa = (pb.z - pb.x) * (pb.w - pb.y);
    const float* cls = (br == 0 ? cls0 : cls1);
    const float* cp = cls + ((size_t)b * NN + n) * NCC;
    float* outbase = alignw + ((size_t)rb * MM) * NN + n;

    for (int m = 0; m < MM; ++m) {
        float g0 = g[4 * m], g1 = g[4 * m + 1], g2 = g[4 * m + 2], g3 = g[4 * m + 3];
        float al = 0.0f;
        if (ax >= g0 && ax <= g2 && ay >= g1 && ay <= g3) {
            float iw = fmaxf(fminf(pb.z, g2) - fmaxf(pb.x, g0), 0.0f);
            float ih = fmaxf(fminf(pb.w, g3) - fmaxf(pb.y, g1), 0.0f);
            float inter = iw * ih;
            float ga = (g2 - g0) * (g3 - g1);
            float iou = inter / (pa + ga - inter + EPSF);
            float x = cp[gl[m]];
            float sig = 1.0f / (1.0f + expf(-x));
            float i2 = iou * iou;
            al = sig * (i2 * i2 * i2);
        }
        outbase[(size_t)m * NN] = al;
    }
}

// ---- kernel 3: single-pass top-k per (branch,b,m) row ----------------------
// key = (float_bits(v) << 32) | (NN - n): valid since v >= 0; larger key ==
// (greater value, then smaller index) -- exactly lax.top_k tie semantics.
__global__ __launch_bounds__(256) void topk_kernel(
    const float* __restrict__ alignw, int* __restrict__ topk1, int* __restrict__ topk2)
{
    int r = blockIdx.x;                 // 0 .. 2*BB*MM-1
    int br = r / (BB * MM);
    int bm = r - br * (BB * MM);
    const float* row = alignw + (size_t)r * NN;
    int tid = threadIdx.x;

    if (br == 1) {
        // k = 1: packed-key max reduce
        unsigned long long best = 0ull;
        for (int n = tid; n < NN; n += 256) {
            unsigned long long key =
                ((unsigned long long)__float_as_uint(row[n]) << 32) | (unsigned)(NN - n);
            if (key > best) best = key;
        }
        for (int o = 32; o > 0; o >>= 1) {
            unsigned long long ov = __shfl_down(best, o, 64);
            if (ov > best) best = ov;
        }
        __shared__ unsigned long long sm[4];
        int lane = tid & 63, w = tid >> 6;
        if (lane == 0) sm[w] = best;
        __syncthreads();
        if (tid == 0) {
            best = sm[0];
            for (int j = 1; j < 4; ++j) if (sm[j] > best) best = sm[j];
            topk2[bm] = NN - (int)(best & 0xffffffffull);
        }
        return;
    }

    // k = 10: per-thread sorted top-10 (desc), then tree merge in LDS
    unsigned long long loc[10];
#pragma unroll
    for (int j = 0; j < 10; ++j) loc[j] = 0ull;   // sentinel: worse than any real key
    for (int n = tid; n < NN; n += 256) {
        unsigned long long key =
            ((unsigned long long)__float_as_uint(row[n]) << 32) | (unsigned)(NN - n);
        if (key > loc[9]) {
            int j = 9;
            while (j > 0 && loc[j - 1] < key) { loc[j] = loc[j - 1]; --j; }
            loc[j] = key;
        }
    }

    __shared__ unsigned long long ls[256 * 10];
#pragma unroll
    for (int j = 0; j < 10; ++j) ls[tid * 10 + j] = loc[j];
    __syncthreads();

    for (int s = 128; s > 0; s >>= 1) {
        if (tid < s) {
            unsigned long long* A = &ls[tid * 10];
            unsigned long long* B2 = &ls[(tid + s) * 10];
            unsigned long long o[10];
            int ia = 0, ib = 0;
#pragma unroll
            for (int j = 0; j < 10; ++j) {
                unsigned long long av = A[ia], bv = B2[ib];
                if (av >= bv) { o[j] = av; ++ia; }
                else          { o[j] = bv; ++ib; }
            }
#pragma unroll
            for (int j = 0; j < 10; ++j) A[j] = o[j];
        }
        __syncthreads();
    }
    if (tid < 10) topk1[bm * 10 + tid] = NN - (int)(ls[tid] & 0xffffffffull);
}

// ---- kernel 4: per-anchor assignment ---------------------------------------
__global__ __launch_bounds__(256) void assign_kernel(
    const float* __restrict__ alignw, const int* __restrict__ topk1,
    const int* __restrict__ topk2, const float* __restrict__ mask_gt,
    int* __restrict__ tgi, float* __restrict__ mposw)
{
    int i = blockIdx.x * 256 + threadIdx.x;
    if (i >= 2 * BB * NN) return;
    int br = i / (BB * NN);
    int bn = i - br * (BB * NN);
    int b = bn / NN;
    int n = bn - b * NN;

    const float* col = alignw + ((size_t)(br * BB + b) * MM) * NN + n;
    float best = col[0];
    int mi = 0;
    for (int m = 1; m < MM; ++m) {
        float v = col[(size_t)m * NN];
        if (v > best) { best = v; mi = m; }
    }
    int ind = 0;
    if (br == 0) {
        const int* tk = topk1 + (b * MM + mi) * 10;
        for (int j = 0; j < 10; ++j)
            if (tk[j] == n) ind = 1;
    } else {
        if (topk2[b * MM + mi] == n) ind = 1;
    }
    float tm = ind ? mask_gt[b * MM + mi] : 0.0f;
    tgi[i] = (tm > 0.0f) ? mi : 0;
    mposw[i] = tm;
}

// ---- block reduce helper ---------------------------------------------------
__device__ inline float blockReduceSum(float v, float* sh) {
    for (int o = 32; o > 0; o >>= 1) v += __shfl_down(v, o, 64);
    int lane = threadIdx.x & 63;
    int w = threadIdx.x >> 6;
    __syncthreads();
    if (lane == 0) sh[w] = v;
    __syncthreads();
    float r = 0.0f;
    if (threadIdx.x == 0) r = sh[0] + sh[1] + sh[2] + sh[3];
    return r;
}

// ---- kernel 5a: sum of softplus over all cls scores (one branch) -----------
__global__ __launch_bounds__(256) void softplus_kernel(
    const float* __restrict__ cls, float* __restrict__ acc_slot)
{
    size_t total4 = (size_t)BB * NN * NCC / 4;
    float s = 0.0f;
    for (size_t i = (size_t)blockIdx.x * 256 + threadIdx.x; i < total4;
         i += (size_t)gridDim.x * 256) {
        float4 v = ((const float4*)cls)[i];
        s += fmaxf(v.x, 0.0f) + log1pf(expf(-fabsf(v.x)));
        s += fmaxf(v.y, 0.0f) + log1pf(expf(-fabsf(v.y)));
        s += fmaxf(v.z, 0.0f) + log1pf(expf(-fabsf(v.z)));
        s += fmaxf(v.w, 0.0f) + log1pf(expf(-fabsf(v.w)));
    }
    __shared__ float sh[4];
    float r = blockReduceSum(s, sh);
    if (threadIdx.x == 0) atomicAdd(acc_slot, r);
}

// ---- kernel 5b: assignment-dependent loss terms ----------------------------
__global__ __launch_bounds__(256) void loss_kernel(
    const float* __restrict__ cls0, const float* __restrict__ cls1,
    const float* __restrict__ regs0, const float* __restrict__ regs1,
    const float* __restrict__ anchors, const float* __restrict__ strides,
    const int* __restrict__ gt_labels, const float* __restrict__ gt_bboxes,
    const float* __restrict__ pdbox, const float* __restrict__ lse,
    const int* __restrict__ tgi, const float* __restrict__ mposw,
    float* __restrict__ acc)
{
    int i = blockIdx.x * 256 + threadIdx.x;
    int br0 = (blockIdx.x * 256) / (BB * NN);   // whole block is in one branch

    float sxt = 0.0f, sbox = 0.0f, sdfl = 0.0f, sfg = 0.0f, smp = 0.0f;
    if (i < 2 * BB * NN) {
        int br = i / (BB * NN);
        int bn = i - br * (BB * NN);
        int b = bn / NN;
        int n = bn - b * NN;
        float mp = mposw[i];
        smp = mp;
        if (mp > 0.0f) {
            sfg = 1.0f;
            int gi = tgi[i];
            const float* gt = gt_bboxes + (size_t)(b * MM + gi) * 4;
            float t0 = gt[0] * mp, t1 = gt[1] * mp, t2 = gt[2] * mp, t3 = gt[3] * mp;
            float4 pb = ((const float4*)pdbox)[i];

            // plain IoU (for tscores)
            float iw = fmaxf(fminf(pb.z, t2) - fmaxf(pb.x, t0), 0.0f);
            float ih = fmaxf(fminf(pb.w, t3) - fmaxf(pb.y, t1), 0.0f);
            float inter = iw * ih;
            float w1 = pb.z - pb.x, h1 = pb.w - pb.y;
            float w2 = t2 - t0, h2 = t3 - t1;
            float uni = w1 * h1 + w2 * h2 - inter + EPSF;
            float iou = inter / uni;

            // -x*t term of BCE
            int lab = gt_labels[b * MM + gi];
            const float* cls = (br == 0 ? cls0 : cls1);
            float x = cls[((size_t)b * NN + n) * NCC + lab];
            sxt = x * iou;

            // CIoU (replicating reference's ch bug: ch = max(y2) - b1y1)
            float cw = fmaxf(pb.z, t2) - fminf(pb.x, t0);
            float ch = fmaxf(pb.w, t3) - pb.y;     // BUG in reference, replicated
            float c2 = cw * cw + ch * ch + EPSF;
            float dx = pb.x + pb.z - t0 - t2;
            float dy = pb.y + pb.w - t1 - t3;
            float rho2 = (dx * dx + dy * dy) * 0.25f;
            float dat = atanf(w2 / (h2 + EPSF)) - atanf(w1 / (h1 + EPSF));
            float v = 0.40528473f * dat * dat;     // 4/pi^2
            float alpha_ = v / (v - iou + 1.0000001f);
            float ciou = iou - (rho2 / c2 + v * alpha_);
            sbox = 1.0f - ciou;

            // DFL
            float st = strides[n];
            float ax = anchors[2 * n], ay = anchors[2 * n + 1];
            float tb[4] = {(ax - t0) / st, (ay - t1) / st,
                           (t2 - ax) / st, (t3 - ay) / st};
            float4 l4 = ((const float4*)lse)[i];
            float lv[4] = {l4.x, l4.y, l4.z, l4.w};
            const float* regs = (br == 0 ? regs0 : regs1) + (size_t)bn * 64;
            float dsum = 0.0f;
#pragma unroll
            for (int s2 = 0; s2 < 4; ++s2) {
                float t = fminf(fmaxf(tb[s2], 0.0f), (float)RMM - 1.01f);
                int tl = (int)t;
                float wl = (float)(tl + 1) - t;
                float wr = 1.0f - wl;
                float lp_l = regs[s2 * 16 + tl] - lv[s2];
                float lp_r = regs[s2 * 16 + tl + 1] - lv[s2];
                dsum += -(lp_l * wl + lp_r * wr);
            }
            sdfl = dsum;
        }
    }

    __shared__ float sh[4];
    float vals[5] = {sxt, sbox, sdfl, sfg, smp};
#pragma unroll
    for (int q = 0; q < 5; ++q) {
        float r = blockReduceSum(vals[q], sh);
        if (threadIdx.x == 0) atomicAdd(&acc[br0 * 8 + q], r);
    }
}

// ---- kernel 6: finalize ----------------------------------------------------
__global__ __launch_bounds__(64) void finalize_kernel(
    const float* __restrict__ acc, float* __restrict__ out)
{
    if (threadIdx.x == 0 && blockIdx.x == 0) {
        float t[2], c[2], bx[2], df[2];
        for (int br = 0; br < 2; ++br) {
            const float* a = acc + br * 8;
            float nfg = fmaxf(a[3], 1.0f);
            float lcls = (a[5] - a[0]) / fmaxf(a[4], 1.0f);
            float lbox = a[1] / nfg;
            float ldfl = a[2] / (nfg * 4.0f);
            t[br] = lcls * 1.0f + lbox * 7.5f + ldfl * 1.5f;
            c[br] = lcls;
            bx[br] = lbox;
            df[br] = ldfl;
        }
        out[0] = t[0] + t[1];
        out[1] = c[0] + c[1];
        out[2] = bx[0] + bx[1];
        out[3] = df[0] + df[1];
        out[4] = t[0];
        out[5] = t[1];
    }
}

// ---------------------------------------------------------------------------
extern "C" void kernel_launch(void* const* d_in, const int* in_sizes, int n_in,
                              void* d_out, int out_size, void* d_ws, size_t ws_size,
                              hipStream_t stream) {
    const float* cls0    = (const float*)d_in[0];  // cls_scores
    const float* regs0   = (const float*)d_in[1];  // box_regs
    const float* cls1    = (const float*)d_in[2];  // one2one_cls
    const float* regs1   = (const float*)d_in[3];  // one2one_reg
    const float* anchors = (const float*)d_in[4];
    const float* strides = (const float*)d_in[5];
    const int*   gt_labels = (const int*)d_in[6];
    const float* gt_bboxes = (const float*)d_in[7];
    const float* mask_gt   = (const float*)d_in[8];
    float* out = (float*)d_out;

    float* pdbox  = (float*)d_ws;                       // 2*BB*NN*4
    float* lse    = pdbox + (size_t)2 * BB * NN * 4;    // 2*BB*NN*4
    float* alignw = lse + (size_t)2 * BB * NN * 4;      // 2*BB*MM*NN
    int*   topk1  = (int*)(alignw + (size_t)2 * BB * MM * NN);  // BB*MM*10
    int*   topk2  = topk1 + BB * MM * 10;               // BB*MM
    int*   tgiw   = topk2 + BB * MM;                    // 2*BB*NN
    float* mposw  = (float*)(tgiw + 2 * BB * NN);       // 2*BB*NN
    float* acc    = mposw + 2 * BB * NN;                // 16

    zero_acc_kernel<<<1, 64, 0, stream>>>(acc);

    int total = 2 * BB * NN;           // 268800
    int blocks = (total + 255) / 256;  // 1050

    decode_kernel<<<blocks, 256, 0, stream>>>(regs0, regs1, anchors, strides, pdbox, lse);

    dim3 agrid((NN + 255) / 256, 2 * BB);
    align_kernel<<<agrid, 256, 0, stream>>>(cls0, cls1, anchors, gt_labels, gt_bboxes,
                                            pdbox, alignw);

    topk_kernel<<<2 * BB * MM, 256, 0, stream>>>(alignw, topk1, topk2);

    assign_kernel<<<blocks, 256, 0, stream>>>(alignw, topk1, topk2, mask_gt, tgiw, mposw);

    softplus_kernel<<<2048, 256, 0, stream>>>(cls0, &acc[0 * 8 + 5]);
    softplus_kernel<<<2048, 256, 0, stream>>>(cls1, &acc[1 * 8 + 5]);

    loss_kernel<<<blocks, 256, 0, stream>>>(cls0, cls1, regs0, regs1, anchors, strides,
                                            gt_labels, gt_bboxes, pdbox, lse,
                                            tgiw, mposw, acc);

    finalize_kernel<<<1, 64, 0, stream>>>(acc, out);
}

// Round 3
// 296.879 us; speedup vs baseline: 1.8780x; 1.1762x over previous
//
#include <hip/hip_runtime.h>
#include <math.h>

#define BB 16
#define MM 32
#define NN 8400
#define NCC 80
#define RMM 16
#define EPSF 1e-7f
#define NCHUNK 33            // ceil(8400/256)
#define SPBLOCKS 1024

// ---------------------------------------------------------------------------
// ws layout (floats):
//   pdbox   : 2*BB*NN*4          (4.3 MB)
//   lse     : 2*BB*NN*4          (4.3 MB)
//   align   : 2*BB*MM*NN         (34.4 MB)
//   topk1   : BB*MM*10 (int)
//   topk2   : BB*MM    (int)
//   partial : 2*BB*NCHUNK*8      (assign_loss per-block partials, q0..q4)
//   psp     : SPBLOCKS*2         (softplus per-block partials, per branch)
// No global atomics anywhere: finalize_kernel reduces the partial arrays.
// ---------------------------------------------------------------------------

// ---- kernel 1: decode bboxes + per-side logsumexp --------------------------
__global__ __launch_bounds__(256) void decode_kernel(
    const float* __restrict__ regs0, const float* __restrict__ regs1,
    const float* __restrict__ anchors, const float* __restrict__ strides,
    float* __restrict__ pdbox, float* __restrict__ lse)
{
    int i = blockIdx.x * 256 + threadIdx.x;
    if (i >= 2 * BB * NN) return;
    int br = i / (BB * NN);
    int bn = i - br * (BB * NN);
    int n = bn % NN;
    const float* regs = (br == 0 ? regs0 : regs1) + (size_t)bn * (4 * RMM);
    const float4* p4 = (const float4*)regs;

    float d[4], l[4];
#pragma unroll
    for (int s = 0; s < 4; ++s) {
        float4 a0 = p4[s * 4 + 0];
        float4 a1 = p4[s * 4 + 1];
        float4 a2 = p4[s * 4 + 2];
        float4 a3 = p4[s * 4 + 3];
        float xs[16] = {a0.x, a0.y, a0.z, a0.w, a1.x, a1.y, a1.z, a1.w,
                        a2.x, a2.y, a2.z, a2.w, a3.x, a3.y, a3.z, a3.w};
        float mx = xs[0];
#pragma unroll
        for (int j = 1; j < 16; ++j) mx = fmaxf(mx, xs[j]);
        float se = 0.0f, sd = 0.0f;
#pragma unroll
        for (int j = 0; j < 16; ++j) {
            float e = expf(xs[j] - mx);
            se += e;
            sd += e * (float)j;
        }
        d[s] = sd / se;
        l[s] = mx + logf(se);
    }
    float ax = anchors[2 * n], ay = anchors[2 * n + 1];
    float st = strides[n];
    float4 box;
    box.x = ax - d[0] * st;
    box.y = ay - d[1] * st;
    box.z = ax + d[2] * st;
    box.w = ay + d[3] * st;
    ((float4*)pdbox)[i] = box;
    float4 lv = make_float4(l[0], l[1], l[2], l[3]);
    ((float4*)lse)[i] = lv;
}

// ---- kernel 2: align metric (B,M,N), one block covers all M for an n-chunk -
__global__ __launch_bounds__(256) void align_kernel(
    const float* __restrict__ cls0, const float* __restrict__ cls1,
    const float* __restrict__ anchors,
    const int* __restrict__ gt_labels, const float* __restrict__ gt_bboxes,
    const float* __restrict__ pdbox, float* __restrict__ alignw)
{
    int n = blockIdx.x * 256 + threadIdx.x;
    int rb = blockIdx.y;                 // 0 .. 2*BB-1  (branch*BB + b)
    int br = rb / BB;
    int b = rb - br * BB;

    __shared__ float g[MM * 4];
    __shared__ int gl[MM];
    if (threadIdx.x < MM * 4) g[threadIdx.x] = gt_bboxes[b * MM * 4 + threadIdx.x];
    if (threadIdx.x < MM) gl[threadIdx.x] = gt_labels[b * MM + threadIdx.x];
    __syncthreads();
    if (n >= NN) return;

    float4 pb = ((const float4*)pdbox)[(size_t)rb * NN + n];
    float ax = anchors[2 * n], ay = anchors[2 * n + 1];
    float pa = (pb.z - pb.x) * (pb.w - pb.y);
    const float* cls = (br == 0 ? cls0 : cls1);
    const float* cp = cls + ((size_t)b * NN + n) * NCC;
    float* outbase = alignw + ((size_t)rb * MM) * NN + n;

    for (int m = 0; m < MM; ++m) {
        float g0 = g[4 * m], g1 = g[4 * m + 1], g2 = g[4 * m + 2], g3 = g[4 * m + 3];
        float al = 0.0f;
        if (ax >= g0 && ax <= g2 && ay >= g1 && ay <= g3) {
            float iw = fmaxf(fminf(pb.z, g2) - fmaxf(pb.x, g0), 0.0f);
            float ih = fmaxf(fminf(pb.w, g3) - fmaxf(pb.y, g1), 0.0f);
            float inter = iw * ih;
            float ga = (g2 - g0) * (g3 - g1);
            float iou = inter / (pa + ga - inter + EPSF);
            float x = cp[gl[m]];
            float sig = 1.0f / (1.0f + expf(-x));
            float i2 = iou * iou;
            al = sig * (i2 * i2 * i2);
        }
        outbase[(size_t)m * NN] = al;
    }
}

// ---- kernel 3: single-pass top-k per (branch,b,m) row ----------------------
// key = (float_bits(v) << 32) | (NN - n): valid since v >= 0; larger key ==
// (greater value, then smaller index) -- exactly lax.top_k tie semantics.
__global__ __launch_bounds__(256) void topk_kernel(
    const float* __restrict__ alignw, int* __restrict__ topk1, int* __restrict__ topk2)
{
    int r = blockIdx.x;                 // 0 .. 2*BB*MM-1
    int br = r / (BB * MM);
    int bm = r - br * (BB * MM);
    const float* row = alignw + (size_t)r * NN;
    int tid = threadIdx.x;

    if (br == 1) {
        // k = 1: packed-key max reduce
        unsigned long long best = 0ull;
        for (int n = tid; n < NN; n += 256) {
            unsigned long long key =
                ((unsigned long long)__float_as_uint(row[n]) << 32) | (unsigned)(NN - n);
            if (key > best) best = key;
        }
        for (int o = 32; o > 0; o >>= 1) {
            unsigned long long ov = __shfl_down(best, o, 64);
            if (ov > best) best = ov;
        }
        __shared__ unsigned long long sm[4];
        int lane = tid & 63, w = tid >> 6;
        if (lane == 0) sm[w] = best;
        __syncthreads();
        if (tid == 0) {
            best = sm[0];
            for (int j = 1; j < 4; ++j) if (sm[j] > best) best = sm[j];
            topk2[bm] = NN - (int)(best & 0xffffffffull);
        }
        return;
    }

    // k = 10: per-thread sorted top-10 (desc), then tree merge in LDS
    unsigned long long loc[10];
#pragma unroll
    for (int j = 0; j < 10; ++j) loc[j] = 0ull;   // sentinel: worse than any real key
    for (int n = tid; n < NN; n += 256) {
        unsigned long long key =
            ((unsigned long long)__float_as_uint(row[n]) << 32) | (unsigned)(NN - n);
        if (key > loc[9]) {
            int j = 9;
            while (j > 0 && loc[j - 1] < key) { loc[j] = loc[j - 1]; --j; }
            loc[j] = key;
        }
    }

    __shared__ unsigned long long ls[256 * 10];
#pragma unroll
    for (int j = 0; j < 10; ++j) ls[tid * 10 + j] = loc[j];
    __syncthreads();

    for (int s = 128; s > 0; s >>= 1) {
        if (tid < s) {
            unsigned long long* A = &ls[tid * 10];
            unsigned long long* B2 = &ls[(tid + s) * 10];
            unsigned long long o[10];
            int ia = 0, ib = 0;
#pragma unroll
            for (int j = 0; j < 10; ++j) {
                unsigned long long av = A[ia], bv = B2[ib];
                if (av >= bv) { o[j] = av; ++ia; }
                else          { o[j] = bv; ++ib; }
            }
#pragma unroll
            for (int j = 0; j < 10; ++j) A[j] = o[j];
        }
        __syncthreads();
    }
    if (tid < 10) topk1[bm * 10 + tid] = NN - (int)(ls[tid] & 0xffffffffull);
}

// ---- block reduce helper (result valid on thread 0) ------------------------
__device__ inline float blockReduceSum(float v, float* sh) {
    for (int o = 32; o > 0; o >>= 1) v += __shfl_down(v, o, 64);
    int lane = threadIdx.x & 63;
    int w = threadIdx.x >> 6;
    __syncthreads();
    if (lane == 0) sh[w] = v;
    __syncthreads();
    float r = 0.0f;
    if (threadIdx.x == 0) r = sh[0] + sh[1] + sh[2] + sh[3];
    return r;
}

// ---- kernel 4: fused assignment + loss terms, per-block partials -----------
// grid: (NCHUNK, 2*BB); partial[(rb*NCHUNK + cx)*8 + q], q: 0=sxt 1=box 2=dfl 3=nfg 4=mpos
__global__ __launch_bounds__(256) void assign_loss_kernel(
    const float* __restrict__ alignw, const int* __restrict__ topk1,
    const int* __restrict__ topk2, const float* __restrict__ mask_gt,
    const int* __restrict__ gt_labels, const float* __restrict__ gt_bboxes,
    const float* __restrict__ cls0, const float* __restrict__ cls1,
    const float* __restrict__ regs0, const float* __restrict__ regs1,
    const float* __restrict__ anchors, const float* __restrict__ strides,
    const float* __restrict__ pdbox, const float* __restrict__ lse,
    float* __restrict__ partial)
{
    int cx = blockIdx.x;
    int rb = blockIdx.y;                 // branch*BB + b
    int br = rb / BB;
    int b = rb - br * BB;
    int tid = threadIdx.x;
    int n = cx * 256 + tid;

    __shared__ float g[MM * 4];
    __shared__ int gl[MM];
    __shared__ float gm[MM];
    __shared__ int tk[MM * 10];
    __shared__ int tk2s[MM];
    if (tid < MM * 4) g[tid] = gt_bboxes[b * MM * 4 + tid];
    if (tid < MM) {
        gl[tid] = gt_labels[b * MM + tid];
        gm[tid] = mask_gt[b * MM + tid];
        tk2s[tid] = topk2[b * MM + tid];
    }
    for (int j = tid; j < MM * 10; j += 256) tk[j] = topk1[b * MM * 10 + j];
    __syncthreads();

    float sxt = 0.0f, sbox = 0.0f, sdfl = 0.0f, sfg = 0.0f, smp = 0.0f;
    if (n < NN) {
        const float* col = alignw + ((size_t)rb * MM) * NN + n;
        float best = col[0];
        int mi = 0;
        for (int m = 1; m < MM; ++m) {
            float v = col[(size_t)m * NN];
            if (v > best) { best = v; mi = m; }
        }
        int ind = 0;
        if (br == 0) {
            const int* tkp = &tk[mi * 10];
#pragma unroll
            for (int j = 0; j < 10; ++j)
                if (tkp[j] == n) ind = 1;
        } else {
            if (tk2s[mi] == n) ind = 1;
        }
        float mp = ind ? gm[mi] : 0.0f;
        smp = mp;
        if (mp > 0.0f) {
            sfg = 1.0f;
            float t0 = g[4 * mi] * mp, t1 = g[4 * mi + 1] * mp;
            float t2 = g[4 * mi + 2] * mp, t3 = g[4 * mi + 3] * mp;
            size_t i = (size_t)rb * NN + n;
            float4 pb = ((const float4*)pdbox)[i];

            // plain IoU (for tscores)
            float iw = fmaxf(fminf(pb.z, t2) - fmaxf(pb.x, t0), 0.0f);
            float ih = fmaxf(fminf(pb.w, t3) - fmaxf(pb.y, t1), 0.0f);
            float inter = iw * ih;
            float w1 = pb.z - pb.x, h1 = pb.w - pb.y;
            float w2 = t2 - t0, h2 = t3 - t1;
            float uni = w1 * h1 + w2 * h2 - inter + EPSF;
            float iou = inter / uni;

            // -x*t term of BCE
            const float* cls = (br == 0 ? cls0 : cls1);
            float x = cls[((size_t)b * NN + n) * NCC + gl[mi]];
            sxt = x * iou;

            // CIoU (replicating reference's ch bug: ch = max(y2) - b1y1)
            float cw = fmaxf(pb.z, t2) - fminf(pb.x, t0);
            float ch = fmaxf(pb.w, t3) - pb.y;     // BUG in reference, replicated
            float c2 = cw * cw + ch * ch + EPSF;
            float dx = pb.x + pb.z - t0 - t2;
            float dy = pb.y + pb.w - t1 - t3;
            float rho2 = (dx * dx + dy * dy) * 0.25f;
            float dat = atanf(w2 / (h2 + EPSF)) - atanf(w1 / (h1 + EPSF));
            float v = 0.40528473f * dat * dat;     // 4/pi^2
            float alpha_ = v / (v - iou + 1.0000001f);
            float ciou = iou - (rho2 / c2 + v * alpha_);
            sbox = 1.0f - ciou;

            // DFL
            float st = strides[n];
            float ax = anchors[2 * n], ay = anchors[2 * n + 1];
            float tb[4] = {(ax - t0) / st, (ay - t1) / st,
                           (t2 - ax) / st, (t3 - ay) / st};
            float4 l4 = ((const float4*)lse)[i];
            float lv[4] = {l4.x, l4.y, l4.z, l4.w};
            const float* regs = (br == 0 ? regs0 : regs1) + ((size_t)b * NN + n) * 64;
            float dsum = 0.0f;
#pragma unroll
            for (int s2 = 0; s2 < 4; ++s2) {
                float t = fminf(fmaxf(tb[s2], 0.0f), (float)RMM - 1.01f);
                int tl = (int)t;
                float wl = (float)(tl + 1) - t;
                float wr = 1.0f - wl;
                float lp_l = regs[s2 * 16 + tl] - lv[s2];
                float lp_r = regs[s2 * 16 + tl + 1] - lv[s2];
                dsum += -(lp_l * wl + lp_r * wr);
            }
            sdfl = dsum;
        }
    }

    __shared__ float sh[4];
    float vals[5] = {sxt, sbox, sdfl, sfg, smp};
    float* outp = partial + ((size_t)rb * NCHUNK + cx) * 8;
#pragma unroll
    for (int q = 0; q < 5; ++q) {
        float r = blockReduceSum(vals[q], sh);
        if (tid == 0) outp[q] = r;
        __syncthreads();
    }
}

// ---- kernel 5: softplus sum over BOTH cls tensors, per-block partials ------
__global__ __launch_bounds__(256) void softplus_kernel(
    const float* __restrict__ cls0, const float* __restrict__ cls1,
    float* __restrict__ psp)
{
    const size_t half4 = (size_t)BB * NN * NCC / 4;   // float4 count per branch
    float s0 = 0.0f, s1 = 0.0f;
    for (size_t i = (size_t)blockIdx.x * 256 + threadIdx.x; i < 2 * half4;
         i += (size_t)SPBLOCKS * 256) {
        int br = (i >= half4);
        float4 v = br ? ((const float4*)cls1)[i - half4] : ((const float4*)cls0)[i];
        float s = fmaxf(v.x, 0.0f) + log1pf(expf(-fabsf(v.x)))
                + fmaxf(v.y, 0.0f) + log1pf(expf(-fabsf(v.y)))
                + fmaxf(v.z, 0.0f) + log1pf(expf(-fabsf(v.z)))
                + fmaxf(v.w, 0.0f) + log1pf(expf(-fabsf(v.w)));
        if (br) s1 += s; else s0 += s;
    }
    __shared__ float sh[4];
    float r0 = blockReduceSum(s0, sh);
    __syncthreads();
    float r1 = blockReduceSum(s1, sh);
    if (threadIdx.x == 0) {
        psp[blockIdx.x * 2 + 0] = r0;
        psp[blockIdx.x * 2 + 1] = r1;
    }
}

// ---- kernel 6: finalize (reduce all partials, emit 6 outputs) --------------
__global__ __launch_bounds__(256) void finalize_kernel(
    const float* __restrict__ partial, const float* __restrict__ psp,
    float* __restrict__ out)
{
    int tid = threadIdx.x;
    float s[10];
#pragma unroll
    for (int j = 0; j < 10; ++j) s[j] = 0.0f;
    const int nblk = 2 * BB * NCHUNK;
    for (int blk = tid; blk < nblk; blk += 256) {
        int br = blk / (BB * NCHUNK);
#pragma unroll
        for (int q = 0; q < 5; ++q) s[br * 5 + q] += partial[(size_t)blk * 8 + q];
    }
    float sp0 = 0.0f, sp1 = 0.0f;
    for (int i = tid; i < SPBLOCKS; i += 256) {
        sp0 += psp[2 * i];
        sp1 += psp[2 * i + 1];
    }

    __shared__ float sh[4];
    __shared__ float res[12];
#pragma unroll
    for (int j = 0; j < 10; ++j) {
        float r = blockReduceSum(s[j], sh);
        if (tid == 0) res[j] = r;
        __syncthreads();
    }
    {
        float r = blockReduceSum(sp0, sh);
        if (tid == 0) res[10] = r;
        __syncthreads();
        r = blockReduceSum(sp1, sh);
        if (tid == 0) res[11] = r;
        __syncthreads();
    }

    if (tid == 0) {
        float t[2], c[2], bx[2], df[2];
        for (int br = 0; br < 2; ++br) {
            float a0 = res[br * 5 + 0], a1 = res[br * 5 + 1], a2 = res[br * 5 + 2];
            float a3 = res[br * 5 + 3], a4 = res[br * 5 + 4];
            float sp = res[10 + br];
            float nfg = fmaxf(a3, 1.0f);
            float lcls = (sp - a0) / fmaxf(a4, 1.0f);
            float lbox = a1 / nfg;
            float ldfl = a2 / (nfg * 4.0f);
            t[br] = lcls * 1.0f + lbox * 7.5f + ldfl * 1.5f;
            c[br] = lcls;
            bx[br] = lbox;
            df[br] = ldfl;
        }
        out[0] = t[0] + t[1];
        out[1] = c[0] + c[1];
        out[2] = bx[0] + bx[1];
        out[3] = df[0] + df[1];
        out[4] = t[0];
        out[5] = t[1];
    }
}

// ---------------------------------------------------------------------------
extern "C" void kernel_launch(void* const* d_in, const int* in_sizes, int n_in,
                              void* d_out, int out_size, void* d_ws, size_t ws_size,
                              hipStream_t stream) {
    const float* cls0    = (const float*)d_in[0];  // cls_scores
    const float* regs0   = (const float*)d_in[1];  // box_regs
    const float* cls1    = (const float*)d_in[2];  // one2one_cls
    const float* regs1   = (const float*)d_in[3];  // one2one_reg
    const float* anchors = (const float*)d_in[4];
    const float* strides = (const float*)d_in[5];
    const int*   gt_labels = (const int*)d_in[6];
    const float* gt_bboxes = (const float*)d_in[7];
    const float* mask_gt   = (const float*)d_in[8];
    float* out = (float*)d_out;

    float* pdbox   = (float*)d_ws;                       // 2*BB*NN*4
    float* lse     = pdbox + (size_t)2 * BB * NN * 4;    // 2*BB*NN*4
    float* alignw  = lse + (size_t)2 * BB * NN * 4;      // 2*BB*MM*NN
    int*   topk1   = (int*)(alignw + (size_t)2 * BB * MM * NN);  // BB*MM*10
    int*   topk2   = topk1 + BB * MM * 10;               // BB*MM
    float* partial = (float*)(topk2 + BB * MM);          // 2*BB*NCHUNK*8
    float* psp     = partial + (size_t)2 * BB * NCHUNK * 8;  // SPBLOCKS*2

    int total = 2 * BB * NN;           // 268800
    int blocks = (total + 255) / 256;  // 1050

    decode_kernel<<<blocks, 256, 0, stream>>>(regs0, regs1, anchors, strides, pdbox, lse);

    dim3 agrid(NCHUNK, 2 * BB);
    align_kernel<<<agrid, 256, 0, stream>>>(cls0, cls1, anchors, gt_labels, gt_bboxes,
                                            pdbox, alignw);

    topk_kernel<<<2 * BB * MM, 256, 0, stream>>>(alignw, topk1, topk2);

    assign_loss_kernel<<<agrid, 256, 0, stream>>>(alignw, topk1, topk2, mask_gt,
                                                  gt_labels, gt_bboxes,
                                                  cls0, cls1, regs0, regs1,
                                                  anchors, strides, pdbox, lse, partial);

    softplus_kernel<<<SPBLOCKS, 256, 0, stream>>>(cls0, cls1, psp);

    finalize_kernel<<<1, 256, 0, stream>>>(partial, psp, out);
}

// Round 4
// 246.036 us; speedup vs baseline: 2.2661x; 1.2066x over previous
//
#include <hip/hip_runtime.h>
#include <math.h>

#define BB 16
#define MM 32
#define NN 8400
#define NCC 80
#define RMM 16
#define EPSF 1e-7f
#define NCHUNK 33            // ceil(8400/256)

// ---------------------------------------------------------------------------
// ws layout (floats):
//   pdbox   : 2*BB*NN*4          (4.3 MB)
//   lse     : 2*BB*NN*4          (4.3 MB)
//   align   : 2*BB*MM*NN         (34.4 MB)
//   topk1   : BB*MM*10 (int)
//   topk2   : BB*MM    (int)
//   partial : 2*BB*NCHUNK*8      (assign_loss per-block partials, q0..q4)
//   psp     : 2*BB*NCHUNK       (softplus per-block partials, from align kernel)
// No global atomics anywhere: finalize_kernel reduces the partial arrays.
// ---------------------------------------------------------------------------

__device__ inline float fast_softplus(float x) {
    // max(x,0) + log1p(exp(-|x|)) via hw v_exp_f32 / v_log_f32
    float e = __expf(-fabsf(x));
    return fmaxf(x, 0.0f) + __logf(1.0f + e);
}

// ---- kernel 1: decode bboxes + per-side logsumexp --------------------------
__global__ __launch_bounds__(256) void decode_kernel(
    const float* __restrict__ regs0, const float* __restrict__ regs1,
    const float* __restrict__ anchors, const float* __restrict__ strides,
    float* __restrict__ pdbox, float* __restrict__ lse)
{
    int i = blockIdx.x * 256 + threadIdx.x;
    if (i >= 2 * BB * NN) return;
    int br = i / (BB * NN);
    int bn = i - br * (BB * NN);
    int n = bn % NN;
    const float* regs = (br == 0 ? regs0 : regs1) + (size_t)bn * (4 * RMM);
    const float4* p4 = (const float4*)regs;

    float d[4], l[4];
#pragma unroll
    for (int s = 0; s < 4; ++s) {
        float4 a0 = p4[s * 4 + 0];
        float4 a1 = p4[s * 4 + 1];
        float4 a2 = p4[s * 4 + 2];
        float4 a3 = p4[s * 4 + 3];
        float xs[16] = {a0.x, a0.y, a0.z, a0.w, a1.x, a1.y, a1.z, a1.w,
                        a2.x, a2.y, a2.z, a2.w, a3.x, a3.y, a3.z, a3.w};
        float mx = xs[0];
#pragma unroll
        for (int j = 1; j < 16; ++j) mx = fmaxf(mx, xs[j]);
        float se = 0.0f, sd = 0.0f;
#pragma unroll
        for (int j = 0; j < 16; ++j) {
            float e = __expf(xs[j] - mx);
            se += e;
            sd += e * (float)j;
        }
        d[s] = sd * __builtin_amdgcn_rcpf(se);
        l[s] = mx + __logf(se);
    }
    float ax = anchors[2 * n], ay = anchors[2 * n + 1];
    float st = strides[n];
    float4 box;
    box.x = ax - d[0] * st;
    box.y = ay - d[1] * st;
    box.z = ax + d[2] * st;
    box.w = ay + d[3] * st;
    ((float4*)pdbox)[i] = box;
    float4 lv = make_float4(l[0], l[1], l[2], l[3]);
    ((float4*)lse)[i] = lv;
}

// ---- block reduce helper (result valid on thread 0) ------------------------
__device__ inline float blockReduceSum(float v, float* sh) {
    for (int o = 32; o > 0; o >>= 1) v += __shfl_down(v, o, 64);
    int lane = threadIdx.x & 63;
    int w = threadIdx.x >> 6;
    __syncthreads();
    if (lane == 0) sh[w] = v;
    __syncthreads();
    float r = 0.0f;
    if (threadIdx.x == 0) r = sh[0] + sh[1] + sh[2] + sh[3];
    return r;
}

// ---- kernel 2: align metric (B,M,N) + fused softplus sum -------------------
// grid (NCHUNK, 2*BB). Each thread owns one (branch,b,n): streams its 80-float
// cls row for the softplus partial, computes 32 align metrics.
__global__ __launch_bounds__(256) void align_kernel(
    const float* __restrict__ cls0, const float* __restrict__ cls1,
    const float* __restrict__ anchors,
    const int* __restrict__ gt_labels, const float* __restrict__ gt_bboxes,
    const float* __restrict__ pdbox, float* __restrict__ alignw,
    float* __restrict__ psp)
{
    int tid = threadIdx.x;
    int n = blockIdx.x * 256 + tid;
    int rb = blockIdx.y;                 // 0 .. 2*BB-1  (branch*BB + b)
    int br = rb / BB;
    int b = rb - br * BB;

    __shared__ float g[MM * 4];
    __shared__ int gl[MM];
    if (tid < MM * 4) g[tid] = gt_bboxes[b * MM * 4 + tid];
    if (tid < MM) gl[tid] = gt_labels[b * MM + tid];
    __syncthreads();

    const float* cls = (br == 0 ? cls0 : cls1);
    float sp = 0.0f;

    if (n < NN) {
        const float* cp = cls + ((size_t)b * NN + n) * NCC;
        const float4* cp4 = (const float4*)cp;
#pragma unroll
        for (int j = 0; j < NCC / 4; ++j) {
            float4 v = cp4[j];
            sp += fast_softplus(v.x) + fast_softplus(v.y) +
                  fast_softplus(v.z) + fast_softplus(v.w);
        }

        float4 pb = ((const float4*)pdbox)[(size_t)rb * NN + n];
        float ax = anchors[2 * n], ay = anchors[2 * n + 1];
        float pa = (pb.z - pb.x) * (pb.w - pb.y);
        float* outbase = alignw + ((size_t)rb * MM) * NN + n;

        for (int m = 0; m < MM; ++m) {
            float g0 = g[4 * m], g1 = g[4 * m + 1], g2 = g[4 * m + 2], g3 = g[4 * m + 3];
            float al = 0.0f;
            if (ax >= g0 && ax <= g2 && ay >= g1 && ay <= g3) {
                float iw = fmaxf(fminf(pb.z, g2) - fmaxf(pb.x, g0), 0.0f);
                float ih = fmaxf(fminf(pb.w, g3) - fmaxf(pb.y, g1), 0.0f);
                float inter = iw * ih;
                float ga = (g2 - g0) * (g3 - g1);
                float iou = inter / (pa + ga - inter + EPSF);
                float x = cp[gl[m]];                       // L1-hot (row just streamed)
                float sig = __builtin_amdgcn_rcpf(1.0f + __expf(-x));
                float i2 = iou * iou;
                al = sig * (i2 * i2 * i2);
            }
            outbase[(size_t)m * NN] = al;
        }
    }

    __shared__ float sh[4];
    float r = blockReduceSum(sp, sh);
    if (tid == 0) psp[(size_t)rb * NCHUNK + blockIdx.x] = r;
}

// ---- kernel 3: single-pass top-k per (branch,b,m) row ----------------------
// key = (float_bits(v) << 32) | (NN - n): valid since v >= 0; larger key ==
// (greater value, then smaller index) -- exactly lax.top_k tie semantics.
__global__ __launch_bounds__(256) void topk_kernel(
    const float* __restrict__ alignw, int* __restrict__ topk1, int* __restrict__ topk2)
{
    int r = blockIdx.x;                 // 0 .. 2*BB*MM-1
    int br = r / (BB * MM);
    int bm = r - br * (BB * MM);
    const float* row = alignw + (size_t)r * NN;
    int tid = threadIdx.x;

    if (br == 1) {
        // k = 1: packed-key max reduce
        unsigned long long best = 0ull;
        for (int n = tid; n < NN; n += 256) {
            unsigned long long key =
                ((unsigned long long)__float_as_uint(row[n]) << 32) | (unsigned)(NN - n);
            if (key > best) best = key;
        }
        for (int o = 32; o > 0; o >>= 1) {
            unsigned long long ov = __shfl_down(best, o, 64);
            if (ov > best) best = ov;
        }
        __shared__ unsigned long long sm[4];
        int lane = tid & 63, w = tid >> 6;
        if (lane == 0) sm[w] = best;
        __syncthreads();
        if (tid == 0) {
            best = sm[0];
            for (int j = 1; j < 4; ++j) if (sm[j] > best) best = sm[j];
            topk2[bm] = NN - (int)(best & 0xffffffffull);
        }
        return;
    }

    // k = 10: per-thread sorted top-10 (desc), then tree merge in LDS
    unsigned long long loc[10];
#pragma unroll
    for (int j = 0; j < 10; ++j) loc[j] = 0ull;   // sentinel: worse than any real key
    for (int n = tid; n < NN; n += 256) {
        unsigned long long key =
            ((unsigned long long)__float_as_uint(row[n]) << 32) | (unsigned)(NN - n);
        if (key > loc[9]) {
            int j = 9;
            while (j > 0 && loc[j - 1] < key) { loc[j] = loc[j - 1]; --j; }
            loc[j] = key;
        }
    }

    __shared__ unsigned long long ls[256 * 10];
#pragma unroll
    for (int j = 0; j < 10; ++j) ls[tid * 10 + j] = loc[j];
    __syncthreads();

    for (int s = 128; s > 0; s >>= 1) {
        if (tid < s) {
            unsigned long long* A = &ls[tid * 10];
            unsigned long long* B2 = &ls[(tid + s) * 10];
            unsigned long long o[10];
            int ia = 0, ib = 0;
#pragma unroll
            for (int j = 0; j < 10; ++j) {
                unsigned long long av = A[ia], bv = B2[ib];
                if (av >= bv) { o[j] = av; ++ia; }
                else          { o[j] = bv; ++ib; }
            }
#pragma unroll
            for (int j = 0; j < 10; ++j) A[j] = o[j];
        }
        __syncthreads();
    }
    if (tid < 10) topk1[bm * 10 + tid] = NN - (int)(ls[tid] & 0xffffffffull);
}

// ---- kernel 4: fused assignment + loss terms, per-block partials -----------
// grid: (NCHUNK, 2*BB); partial[(rb*NCHUNK + cx)*8 + q], q: 0=sxt 1=box 2=dfl 3=nfg 4=mpos
__global__ __launch_bounds__(256) void assign_loss_kernel(
    const float* __restrict__ alignw, const int* __restrict__ topk1,
    const int* __restrict__ topk2, const float* __restrict__ mask_gt,
    const int* __restrict__ gt_labels, const float* __restrict__ gt_bboxes,
    const float* __restrict__ cls0, const float* __restrict__ cls1,
    const float* __restrict__ regs0, const float* __restrict__ regs1,
    const float* __restrict__ anchors, const float* __restrict__ strides,
    const float* __restrict__ pdbox, const float* __restrict__ lse,
    float* __restrict__ partial)
{
    int cx = blockIdx.x;
    int rb = blockIdx.y;                 // branch*BB + b
    int br = rb / BB;
    int b = rb - br * BB;
    int tid = threadIdx.x;
    int n = cx * 256 + tid;

    __shared__ float g[MM * 4];
    __shared__ int gl[MM];
    __shared__ float gm[MM];
    __shared__ int tk[MM * 10];
    __shared__ int tk2s[MM];
    if (tid < MM * 4) g[tid] = gt_bboxes[b * MM * 4 + tid];
    if (tid < MM) {
        gl[tid] = gt_labels[b * MM + tid];
        gm[tid] = mask_gt[b * MM + tid];
        tk2s[tid] = topk2[b * MM + tid];
    }
    for (int j = tid; j < MM * 10; j += 256) tk[j] = topk1[b * MM * 10 + j];
    __syncthreads();

    float sxt = 0.0f, sbox = 0.0f, sdfl = 0.0f, sfg = 0.0f, smp = 0.0f;
    if (n < NN) {
        const float* col = alignw + ((size_t)rb * MM) * NN + n;
        float best = col[0];
        int mi = 0;
        for (int m = 1; m < MM; ++m) {
            float v = col[(size_t)m * NN];
            if (v > best) { best = v; mi = m; }
        }
        int ind = 0;
        if (br == 0) {
            const int* tkp = &tk[mi * 10];
#pragma unroll
            for (int j = 0; j < 10; ++j)
                if (tkp[j] == n) ind = 1;
        } else {
            if (tk2s[mi] == n) ind = 1;
        }
        float mp = ind ? gm[mi] : 0.0f;
        smp = mp;
        if (mp > 0.0f) {
            sfg = 1.0f;
            float t0 = g[4 * mi] * mp, t1 = g[4 * mi + 1] * mp;
            float t2 = g[4 * mi + 2] * mp, t3 = g[4 * mi + 3] * mp;
            size_t i = (size_t)rb * NN + n;
            float4 pb = ((const float4*)pdbox)[i];

            // plain IoU (for tscores)
            float iw = fmaxf(fminf(pb.z, t2) - fmaxf(pb.x, t0), 0.0f);
            float ih = fmaxf(fminf(pb.w, t3) - fmaxf(pb.y, t1), 0.0f);
            float inter = iw * ih;
            float w1 = pb.z - pb.x, h1 = pb.w - pb.y;
            float w2 = t2 - t0, h2 = t3 - t1;
            float uni = w1 * h1 + w2 * h2 - inter + EPSF;
            float iou = inter / uni;

            // -x*t term of BCE
            const float* cls = (br == 0 ? cls0 : cls1);
            float x = cls[((size_t)b * NN + n) * NCC + gl[mi]];
            sxt = x * iou;

            // CIoU (replicating reference's ch bug: ch = max(y2) - b1y1)
            float cw = fmaxf(pb.z, t2) - fminf(pb.x, t0);
            float ch = fmaxf(pb.w, t3) - pb.y;     // BUG in reference, replicated
            float c2 = cw * cw + ch * ch + EPSF;
            float dx = pb.x + pb.z - t0 - t2;
            float dy = pb.y + pb.w - t1 - t3;
            float rho2 = (dx * dx + dy * dy) * 0.25f;
            float dat = atanf(w2 / (h2 + EPSF)) - atanf(w1 / (h1 + EPSF));
            float v = 0.40528473f * dat * dat;     // 4/pi^2
            float alpha_ = v / (v - iou + 1.0000001f);
            float ciou = iou - (rho2 / c2 + v * alpha_);
            sbox = 1.0f - ciou;

            // DFL
            float st = strides[n];
            float ax = anchors[2 * n], ay = anchors[2 * n + 1];
            float tb[4] = {(ax - t0) / st, (ay - t1) / st,
                           (t2 - ax) / st, (t3 - ay) / st};
            float4 l4 = ((const float4*)lse)[i];
            float lv[4] = {l4.x, l4.y, l4.z, l4.w};
            const float* regs = (br == 0 ? regs0 : regs1) + ((size_t)b * NN + n) * 64;
            float dsum = 0.0f;
#pragma unroll
            for (int s2 = 0; s2 < 4; ++s2) {
                float t = fminf(fmaxf(tb[s2], 0.0f), (float)RMM - 1.01f);
                int tl = (int)t;
                float wl = (float)(tl + 1) - t;
                float wr = 1.0f - wl;
                float lp_l = regs[s2 * 16 + tl] - lv[s2];
                float lp_r = regs[s2 * 16 + tl + 1] - lv[s2];
                dsum += -(lp_l * wl + lp_r * wr);
            }
            sdfl = dsum;
        }
    }

    __shared__ float sh[4];
    float vals[5] = {sxt, sbox, sdfl, sfg, smp};
    float* outp = partial + ((size_t)rb * NCHUNK + cx) * 8;
#pragma unroll
    for (int q = 0; q < 5; ++q) {
        float r = blockReduceSum(vals[q], sh);
        if (tid == 0) outp[q] = r;
        __syncthreads();
    }
}

// ---- kernel 5: finalize (reduce all partials, emit 6 outputs) --------------
__global__ __launch_bounds__(256) void finalize_kernel(
    const float* __restrict__ partial, const float* __restrict__ psp,
    float* __restrict__ out)
{
    int tid = threadIdx.x;
    float s[10];
#pragma unroll
    for (int j = 0; j < 10; ++j) s[j] = 0.0f;
    float sp0 = 0.0f, sp1 = 0.0f;
    const int nblk = 2 * BB * NCHUNK;
    for (int blk = tid; blk < nblk; blk += 256) {
        int br = blk / (BB * NCHUNK);
#pragma unroll
        for (int q = 0; q < 5; ++q) s[br * 5 + q] += partial[(size_t)blk * 8 + q];
        float v = psp[blk];
        if (br) sp1 += v; else sp0 += v;
    }

    __shared__ float sh[4];
    __shared__ float res[12];
#pragma unroll
    for (int j = 0; j < 10; ++j) {
        float r = blockReduceSum(s[j], sh);
        if (tid == 0) res[j] = r;
        __syncthreads();
    }
    {
        float r = blockReduceSum(sp0, sh);
        if (tid == 0) res[10] = r;
        __syncthreads();
        r = blockReduceSum(sp1, sh);
        if (tid == 0) res[11] = r;
        __syncthreads();
    }

    if (tid == 0) {
        float t[2], c[2], bx[2], df[2];
        for (int br = 0; br < 2; ++br) {
            float a0 = res[br * 5 + 0], a1 = res[br * 5 + 1], a2 = res[br * 5 + 2];
            float a3 = res[br * 5 + 3], a4 = res[br * 5 + 4];
            float sp = res[10 + br];
            float nfg = fmaxf(a3, 1.0f);
            float lcls = (sp - a0) / fmaxf(a4, 1.0f);
            float lbox = a1 / nfg;
            float ldfl = a2 / (nfg * 4.0f);
            t[br] = lcls * 1.0f + lbox * 7.5f + ldfl * 1.5f;
            c[br] = lcls;
            bx[br] = lbox;
            df[br] = ldfl;
        }
        out[0] = t[0] + t[1];
        out[1] = c[0] + c[1];
        out[2] = bx[0] + bx[1];
        out[3] = df[0] + df[1];
        out[4] = t[0];
        out[5] = t[1];
    }
}

// ---------------------------------------------------------------------------
extern "C" void kernel_launch(void* const* d_in, const int* in_sizes, int n_in,
                              void* d_out, int out_size, void* d_ws, size_t ws_size,
                              hipStream_t stream) {
    const float* cls0    = (const float*)d_in[0];  // cls_scores
    const float* regs0   = (const float*)d_in[1];  // box_regs
    const float* cls1    = (const float*)d_in[2];  // one2one_cls
    const float* regs1   = (const float*)d_in[3];  // one2one_reg
    const float* anchors = (const float*)d_in[4];
    const float* strides = (const float*)d_in[5];
    const int*   gt_labels = (const int*)d_in[6];
    const float* gt_bboxes = (const float*)d_in[7];
    const float* mask_gt   = (const float*)d_in[8];
    float* out = (float*)d_out;

    float* pdbox   = (float*)d_ws;                       // 2*BB*NN*4
    float* lse     = pdbox + (size_t)2 * BB * NN * 4;    // 2*BB*NN*4
    float* alignw  = lse + (size_t)2 * BB * NN * 4;      // 2*BB*MM*NN
    int*   topk1   = (int*)(alignw + (size_t)2 * BB * MM * NN);  // BB*MM*10
    int*   topk2   = topk1 + BB * MM * 10;               // BB*MM
    float* partial = (float*)(topk2 + BB * MM);          // 2*BB*NCHUNK*8
    float* psp     = partial + (size_t)2 * BB * NCHUNK * 8;  // 2*BB*NCHUNK

    int total = 2 * BB * NN;           // 268800
    int blocks = (total + 255) / 256;  // 1050

    decode_kernel<<<blocks, 256, 0, stream>>>(regs0, regs1, anchors, strides, pdbox, lse);

    dim3 agrid(NCHUNK, 2 * BB);
    align_kernel<<<agrid, 256, 0, stream>>>(cls0, cls1, anchors, gt_labels, gt_bboxes,
                                            pdbox, alignw, psp);

    topk_kernel<<<2 * BB * MM, 256, 0, stream>>>(alignw, topk1, topk2);

    assign_loss_kernel<<<agrid, 256, 0, stream>>>(alignw, topk1, topk2, mask_gt,
                                                  gt_labels, gt_bboxes,
                                                  cls0, cls1, regs0, regs1,
                                                  anchors, strides, pdbox, lse, partial);

    finalize_kernel<<<1, 256, 0, stream>>>(partial, psp, out);
}

// Round 5
// 233.265 us; speedup vs baseline: 2.3901x; 1.0547x over previous
//
#include <hip/hip_runtime.h>
#include <math.h>

#define BB 16
#define MM 32
#define NN 8400
#define NCC 80
#define RMM 16
#define EPSF 1e-7f
#define NCHUNK 33            // ceil(8400/256)

// ---------------------------------------------------------------------------
// ws layout (floats):
//   pdbox   : 2*BB*NN*4   (component-per-lane layout, [rb*NN+n][4])
//   lse     : 2*BB*NN*4
//   topk1   : BB*MM*10 (int)
//   topk2   : BB*MM    (int)
//   partial : 2*BB*NCHUNK*8   (assign_loss per-block partials, q0..q4)
//   psp     : 2*BB*NCHUNK     (softplus per-block partials)
// No align matrix, no global atomics.
// ---------------------------------------------------------------------------

__device__ inline unsigned long long ullmax(unsigned long long a, unsigned long long b) {
    return a > b ? a : b;
}
__device__ inline unsigned long long ullmin(unsigned long long a, unsigned long long b) {
    return a < b ? a : b;
}

// Shared align-metric computation. __noinline__ => ONE codegen => bit-identical
// values in align_topk_kernel and assign_loss_kernel (required: assign's
// argmax must agree with topk's ordering on the same logical values).
__device__ __noinline__ float align_val(
    float px, float py, float pz, float pw,
    float g0, float g1, float g2, float g3, float x)
{
    float iw = fmaxf(fminf(pz, g2) - fmaxf(px, g0), 0.0f);
    float ih = fmaxf(fminf(pw, g3) - fmaxf(py, g1), 0.0f);
    float inter = iw * ih;
    float pa = (pz - px) * (pw - py);
    float ga = (g2 - g0) * (g3 - g1);
    float iou = inter / (pa + ga - inter + EPSF);
    float sig = __builtin_amdgcn_rcpf(1.0f + __expf(-x));
    float i2 = iou * iou;
    return sig * (i2 * i2 * i2);
}

__device__ inline float fast_softplus(float x) {
    float e = __expf(-fabsf(x));
    return fmaxf(x, 0.0f) + __logf(1.0f + e);
}

// ---- kernel 1: decode. 1 thread per (branch,b,n,side): 64B coalesced read,
// softmax-16, component-per-lane write (zero cross-lane traffic). ------------
__global__ __launch_bounds__(256) void decode_kernel(
    const float* __restrict__ regs0, const float* __restrict__ regs1,
    const float* __restrict__ anchors, const float* __restrict__ strides,
    float* __restrict__ pdbox, float* __restrict__ lse)
{
    int i = blockIdx.x * 256 + threadIdx.x;     // a*4 + s
    if (i >= 2 * BB * NN * 4) return;
    int s = i & 3;
    int a = i >> 2;
    int br = a / (BB * NN);
    int bn = a - br * (BB * NN);
    int n = bn % NN;

    const float4* p4 = (const float4*)((br == 0 ? regs0 : regs1) + (size_t)bn * 64 + s * 16);
    float4 a0 = p4[0], a1 = p4[1], a2 = p4[2], a3 = p4[3];
    float xs[16] = {a0.x, a0.y, a0.z, a0.w, a1.x, a1.y, a1.z, a1.w,
                    a2.x, a2.y, a2.z, a2.w, a3.x, a3.y, a3.z, a3.w};
    float mx = xs[0];
#pragma unroll
    for (int j = 1; j < 16; ++j) mx = fmaxf(mx, xs[j]);
    float se = 0.0f, sd = 0.0f;
#pragma unroll
    for (int j = 0; j < 16; ++j) {
        float e = __expf(xs[j] - mx);
        se += e;
        sd += e * (float)j;
    }
    float d = sd * __builtin_amdgcn_rcpf(se);
    float l = mx + __logf(se);

    float anc = ((s & 1) == 0) ? anchors[2 * n] : anchors[2 * n + 1];
    float st = strides[n];
    pdbox[i] = (s < 2) ? (anc - d * st) : (anc + d * st);
    lse[i] = l;
}

// ---- kernel 2: fused align + top-k. One block per (branch,b,m) row. --------
// key = (float_bits(al) << 32) | (NN - n): al >= 0, so bigger key ==
// (greater value, then smaller index) — exact lax.top_k tie semantics.
__global__ __launch_bounds__(256) void align_topk_kernel(
    const float* __restrict__ cls0, const float* __restrict__ cls1,
    const float* __restrict__ anchors,
    const int* __restrict__ gt_labels, const float* __restrict__ gt_bboxes,
    const float* __restrict__ pdbox,
    int* __restrict__ topk1, int* __restrict__ topk2)
{
    int r = blockIdx.x;                 // 0 .. 2*BB*MM-1
    int br = r / (BB * MM);
    int bm = r - br * (BB * MM);
    int b = bm / MM;
    int tid = threadIdx.x;

    const float* gt = gt_bboxes + (size_t)bm * 4;
    float g0 = gt[0], g1 = gt[1], g2 = gt[2], g3 = gt[3];
    int lab = gt_labels[bm];
    const float* clscol = (br == 0 ? cls0 : cls1) + (size_t)b * NN * NCC + lab;
    const float4* pb4 = (const float4*)pdbox + (size_t)(br * BB + b) * NN;
    const float2* anc2 = (const float2*)anchors;

    if (br == 1) {
        // k = 1: packed-key max reduce
        unsigned long long best = 0ull;
        for (int n = tid; n < NN; n += 256) {
            float2 anc = anc2[n];
            unsigned long long key = (unsigned long long)(unsigned)(NN - n);
            if (anc.x >= g0 && anc.x <= g2 && anc.y >= g1 && anc.y <= g3) {
                float4 pb = pb4[n];
                float x = clscol[(size_t)n * NCC];
                float al = align_val(pb.x, pb.y, pb.z, pb.w, g0, g1, g2, g3, x);
                key |= ((unsigned long long)__float_as_uint(al) << 32);
            }
            if (key > best) best = key;
        }
        for (int o = 32; o > 0; o >>= 1) best = ullmax(best, __shfl_down(best, o, 64));
        __shared__ unsigned long long sm[4];
        int lane = tid & 63, w = tid >> 6;
        if (lane == 0) sm[w] = best;
        __syncthreads();
        if (tid == 0) {
            best = ullmax(ullmax(sm[0], sm[1]), ullmax(sm[2], sm[3]));
            topk2[bm] = NN - (int)(best & 0xffffffffull);
        }
        return;
    }

    // k = 10: branchless per-thread sorted top-10 (static indices, no spill),
    // then LDS tree merge.
    unsigned long long loc[10];
#pragma unroll
    for (int j = 0; j < 10; ++j) loc[j] = 0ull;
    for (int n = tid; n < NN; n += 256) {
        float2 anc = anc2[n];
        unsigned long long key = (unsigned long long)(unsigned)(NN - n);
        if (anc.x >= g0 && anc.x <= g2 && anc.y >= g1 && anc.y <= g3) {
            float4 pb = pb4[n];
            float x = clscol[(size_t)n * NCC];
            float al = align_val(pb.x, pb.y, pb.z, pb.w, g0, g1, g2, g3, x);
            key |= ((unsigned long long)__float_as_uint(al) << 32);
        }
        if (key > loc[9]) {
#pragma unroll
            for (int j = 9; j >= 1; --j)
                loc[j] = ullmax(loc[j], ullmin(loc[j - 1], key));
            loc[0] = ullmax(loc[0], key);
        }
    }

    __shared__ unsigned long long ls[256 * 10];
#pragma unroll
    for (int j = 0; j < 10; ++j) ls[tid * 10 + j] = loc[j];
    __syncthreads();

    for (int s = 128; s > 0; s >>= 1) {
        if (tid < s) {
            unsigned long long* A = &ls[tid * 10];
            unsigned long long* B2 = &ls[(tid + s) * 10];
            unsigned long long o[10];
            int ia = 0, ib = 0;
#pragma unroll
            for (int j = 0; j < 10; ++j) {
                unsigned long long av = A[ia], bv = B2[ib];
                if (av >= bv) { o[j] = av; ++ia; }
                else          { o[j] = bv; ++ib; }
            }
#pragma unroll
            for (int j = 0; j < 10; ++j) A[j] = o[j];
        }
        __syncthreads();
    }
    if (tid < 10) topk1[bm * 10 + tid] = NN - (int)(ls[tid] & 0xffffffffull);
}

// ---- block reduce helper (result valid on thread 0) ------------------------
__device__ inline float blockReduceSum(float v, float* sh) {
    for (int o = 32; o > 0; o >>= 1) v += __shfl_down(v, o, 64);
    int lane = threadIdx.x & 63;
    int w = threadIdx.x >> 6;
    __syncthreads();
    if (lane == 0) sh[w] = v;
    __syncthreads();
    float r = 0.0f;
    if (threadIdx.x == 0) r = sh[0] + sh[1] + sh[2] + sh[3];
    return r;
}

// ---- kernel 3: assignment (column align recomputed) + losses + softplus ----
// grid: (NCHUNK, 2*BB); partial[(rb*NCHUNK+cx)*8+q], q: 0=sxt 1=box 2=dfl 3=nfg 4=mpos
__global__ __launch_bounds__(256) void assign_loss_kernel(
    const int* __restrict__ topk1, const int* __restrict__ topk2,
    const float* __restrict__ mask_gt,
    const int* __restrict__ gt_labels, const float* __restrict__ gt_bboxes,
    const float* __restrict__ cls0, const float* __restrict__ cls1,
    const float* __restrict__ regs0, const float* __restrict__ regs1,
    const float* __restrict__ anchors, const float* __restrict__ strides,
    const float* __restrict__ pdbox, const float* __restrict__ lse,
    float* __restrict__ partial, float* __restrict__ psp)
{
    int cx = blockIdx.x;
    int rb = blockIdx.y;                 // branch*BB + b
    int br = rb / BB;
    int b = rb - br * BB;
    int tid = threadIdx.x;
    int n = cx * 256 + tid;

    __shared__ float g[MM * 4];
    __shared__ int gl[MM];
    __shared__ float gm[MM];
    __shared__ int tk[MM * 10];
    __shared__ int tk2s[MM];
    if (tid < MM * 4) g[tid] = gt_bboxes[b * MM * 4 + tid];
    if (tid < MM) {
        gl[tid] = gt_labels[b * MM + tid];
        gm[tid] = mask_gt[b * MM + tid];
        tk2s[tid] = topk2[b * MM + tid];
    }
    for (int j = tid; j < MM * 10; j += 256) tk[j] = topk1[b * MM * 10 + j];
    __syncthreads();

    const float* cls = (br == 0 ? cls0 : cls1);
    float sp = 0.0f;
    float sxt = 0.0f, sbox = 0.0f, sdfl = 0.0f, sfg = 0.0f, smp = 0.0f;

    if (n < NN) {
        // softplus stream over this (b,n)'s 80 cls logits
        const float* cp = cls + ((size_t)b * NN + n) * NCC;
        const float4* cp4 = (const float4*)cp;
#pragma unroll
        for (int j = 0; j < NCC / 4; ++j) {
            float4 v = cp4[j];
            sp += fast_softplus(v.x) + fast_softplus(v.y) +
                  fast_softplus(v.z) + fast_softplus(v.w);
        }

        float2 anc = ((const float2*)anchors)[n];
        size_t i = (size_t)rb * NN + n;
        float4 pb = ((const float4*)pdbox)[i];

        // column argmax over m, align recomputed (bit-identical to topk's)
        float best = 0.0f;
        int mi = 0;
        for (int m = 0; m < MM; ++m) {
            float g0 = g[4 * m], g1 = g[4 * m + 1], g2 = g[4 * m + 2], g3 = g[4 * m + 3];
            if (anc.x >= g0 && anc.x <= g2 && anc.y >= g1 && anc.y <= g3) {
                float x = cp[gl[m]];
                float al = align_val(pb.x, pb.y, pb.z, pb.w, g0, g1, g2, g3, x);
                if (al > best) { best = al; mi = m; }
            }
        }

        int ind = 0;
        if (br == 0) {
            const int* tkp = &tk[mi * 10];
#pragma unroll
            for (int j = 0; j < 10; ++j)
                if (tkp[j] == n) ind = 1;
        } else {
            if (tk2s[mi] == n) ind = 1;
        }
        float mp = ind ? gm[mi] : 0.0f;
        smp = mp;
        if (mp > 0.0f) {
            sfg = 1.0f;
            float t0 = g[4 * mi] * mp, t1 = g[4 * mi + 1] * mp;
            float t2 = g[4 * mi + 2] * mp, t3 = g[4 * mi + 3] * mp;

            // plain IoU (for tscores)
            float iw = fmaxf(fminf(pb.z, t2) - fmaxf(pb.x, t0), 0.0f);
            float ih = fmaxf(fminf(pb.w, t3) - fmaxf(pb.y, t1), 0.0f);
            float inter = iw * ih;
            float w1 = pb.z - pb.x, h1 = pb.w - pb.y;
            float w2 = t2 - t0, h2 = t3 - t1;
            float uni = w1 * h1 + w2 * h2 - inter + EPSF;
            float iou = inter / uni;

            // -x*t term of BCE
            float x = cp[gl[mi]];
            sxt = x * iou;

            // CIoU (replicating reference's ch bug: ch = max(y2) - b1y1)
            float cw = fmaxf(pb.z, t2) - fminf(pb.x, t0);
            float ch = fmaxf(pb.w, t3) - pb.y;     // BUG in reference, replicated
            float c2 = cw * cw + ch * ch + EPSF;
            float dx = pb.x + pb.z - t0 - t2;
            float dy = pb.y + pb.w - t1 - t3;
            float rho2 = (dx * dx + dy * dy) * 0.25f;
            float dat = atanf(w2 / (h2 + EPSF)) - atanf(w1 / (h1 + EPSF));
            float v = 0.40528473f * dat * dat;     // 4/pi^2
            float alpha_ = v / (v - iou + 1.0000001f);
            float ciou = iou - (rho2 / c2 + v * alpha_);
            sbox = 1.0f - ciou;

            // DFL
            float st = strides[n];
            float tb[4] = {(anc.x - t0) / st, (anc.y - t1) / st,
                           (t2 - anc.x) / st, (t3 - anc.y) / st};
            float4 l4 = ((const float4*)lse)[i];
            float lv[4] = {l4.x, l4.y, l4.z, l4.w};
            const float* regs = (br == 0 ? regs0 : regs1) + ((size_t)b * NN + n) * 64;
            float dsum = 0.0f;
#pragma unroll
            for (int s2 = 0; s2 < 4; ++s2) {
                float t = fminf(fmaxf(tb[s2], 0.0f), (float)RMM - 1.01f);
                int tl = (int)t;
                float wl = (float)(tl + 1) - t;
                float wr = 1.0f - wl;
                float lp_l = regs[s2 * 16 + tl] - lv[s2];
                float lp_r = regs[s2 * 16 + tl + 1] - lv[s2];
                dsum += -(lp_l * wl + lp_r * wr);
            }
            sdfl = dsum;
        }
    }

    __shared__ float sh[4];
    float vals[5] = {sxt, sbox, sdfl, sfg, smp};
    float* outp = partial + ((size_t)rb * NCHUNK + cx) * 8;
#pragma unroll
    for (int q = 0; q < 5; ++q) {
        float r = blockReduceSum(vals[q], sh);
        if (tid == 0) outp[q] = r;
        __syncthreads();
    }
    float rsp = blockReduceSum(sp, sh);
    if (tid == 0) psp[(size_t)rb * NCHUNK + cx] = rsp;
}

// ---- kernel 4: finalize (reduce all partials, emit 6 outputs) --------------
__global__ __launch_bounds__(256) void finalize_kernel(
    const float* __restrict__ partial, const float* __restrict__ psp,
    float* __restrict__ out)
{
    int tid = threadIdx.x;
    float s[10];
#pragma unroll
    for (int j = 0; j < 10; ++j) s[j] = 0.0f;
    float sp0 = 0.0f, sp1 = 0.0f;
    const int nblk = 2 * BB * NCHUNK;
    for (int blk = tid; blk < nblk; blk += 256) {
        int br = blk / (BB * NCHUNK);
#pragma unroll
        for (int q = 0; q < 5; ++q) s[br * 5 + q] += partial[(size_t)blk * 8 + q];
        float v = psp[blk];
        if (br) sp1 += v; else sp0 += v;
    }

    __shared__ float sh[4];
    __shared__ float res[12];
#pragma unroll
    for (int j = 0; j < 10; ++j) {
        float r = blockReduceSum(s[j], sh);
        if (tid == 0) res[j] = r;
        __syncthreads();
    }
    {
        float r = blockReduceSum(sp0, sh);
        if (tid == 0) res[10] = r;
        __syncthreads();
        r = blockReduceSum(sp1, sh);
        if (tid == 0) res[11] = r;
        __syncthreads();
    }

    if (tid == 0) {
        float t[2], c[2], bx[2], df[2];
        for (int br = 0; br < 2; ++br) {
            float a0 = res[br * 5 + 0], a1 = res[br * 5 + 1], a2 = res[br * 5 + 2];
            float a3 = res[br * 5 + 3], a4 = res[br * 5 + 4];
            float sp = res[10 + br];
            float nfg = fmaxf(a3, 1.0f);
            float lcls = (sp - a0) / fmaxf(a4, 1.0f);
            float lbox = a1 / nfg;
            float ldfl = a2 / (nfg * 4.0f);
            t[br] = lcls * 1.0f + lbox * 7.5f + ldfl * 1.5f;
            c[br] = lcls;
            bx[br] = lbox;
            df[br] = ldfl;
        }
        out[0] = t[0] + t[1];
        out[1] = c[0] + c[1];
        out[2] = bx[0] + bx[1];
        out[3] = df[0] + df[1];
        out[4] = t[0];
        out[5] = t[1];
    }
}

// ---------------------------------------------------------------------------
extern "C" void kernel_launch(void* const* d_in, const int* in_sizes, int n_in,
                              void* d_out, int out_size, void* d_ws, size_t ws_size,
                              hipStream_t stream) {
    const float* cls0    = (const float*)d_in[0];  // cls_scores
    const float* regs0   = (const float*)d_in[1];  // box_regs
    const float* cls1    = (const float*)d_in[2];  // one2one_cls
    const float* regs1   = (const float*)d_in[3];  // one2one_reg
    const float* anchors = (const float*)d_in[4];
    const float* strides = (const float*)d_in[5];
    const int*   gt_labels = (const int*)d_in[6];
    const float* gt_bboxes = (const float*)d_in[7];
    const float* mask_gt   = (const float*)d_in[8];
    float* out = (float*)d_out;

    float* pdbox   = (float*)d_ws;                       // 2*BB*NN*4
    float* lse     = pdbox + (size_t)2 * BB * NN * 4;    // 2*BB*NN*4
    int*   topk1   = (int*)(lse + (size_t)2 * BB * NN * 4);  // BB*MM*10
    int*   topk2   = topk1 + BB * MM * 10;               // BB*MM
    float* partial = (float*)(topk2 + BB * MM);          // 2*BB*NCHUNK*8
    float* psp     = partial + (size_t)2 * BB * NCHUNK * 8;  // 2*BB*NCHUNK

    int dthreads = 2 * BB * NN * 4;        // 1,075,200
    decode_kernel<<<(dthreads + 255) / 256, 256, 0, stream>>>(
        regs0, regs1, anchors, strides, pdbox, lse);

    align_topk_kernel<<<2 * BB * MM, 256, 0, stream>>>(
        cls0, cls1, anchors, gt_labels, gt_bboxes, pdbox, topk1, topk2);

    dim3 agrid(NCHUNK, 2 * BB);
    assign_loss_kernel<<<agrid, 256, 0, stream>>>(
        topk1, topk2, mask_gt, gt_labels, gt_bboxes,
        cls0, cls1, regs0, regs1, anchors, strides, pdbox, lse, partial, psp);

    finalize_kernel<<<1, 256, 0, stream>>>(partial, psp, out);
}

// Round 6
// 230.648 us; speedup vs baseline: 2.4173x; 1.0113x over previous
//
#include <hip/hip_runtime.h>
#include <math.h>

#define BB 16
#define MM 32
#define NN 8400
#define NCC 80
#define RMM 16
#define EPSF 1e-7f
#define NCHUNK 33            // ceil(8400/256)
#define DBLOCKS 4200         // decode grid: 2*BB*NN*4 / 256 exactly

// ---------------------------------------------------------------------------
// ws layout (floats):
//   pdbox   : 2*BB*NN*4   ([rb*NN+n][4])
//   lse     : 2*BB*NN*4
//   topk1   : BB*MM*10 (int)
//   topk2   : BB*MM    (int)
//   partial : 2*BB*NCHUNK*8   (assign_loss per-block partials, q0..q4)
//   psp     : DBLOCKS*2       (softplus per-block partials, from decode)
// No align matrix, no global atomics.
// ---------------------------------------------------------------------------

__device__ inline unsigned long long ullmax(unsigned long long a, unsigned long long b) {
    return a > b ? a : b;
}
__device__ inline unsigned long long ullmin(unsigned long long a, unsigned long long b) {
    return a < b ? a : b;
}

// Shared align-metric computation. __noinline__ => ONE codegen => bit-identical
// values in align_topk_kernel and assign_loss_kernel (required: assign's
// argmax must agree with topk's ordering on the same logical values).
__device__ __noinline__ float align_val(
    float px, float py, float pz, float pw,
    float g0, float g1, float g2, float g3, float x)
{
    float iw = fmaxf(fminf(pz, g2) - fmaxf(px, g0), 0.0f);
    float ih = fmaxf(fminf(pw, g3) - fmaxf(py, g1), 0.0f);
    float inter = iw * ih;
    float pa = (pz - px) * (pw - py);
    float ga = (g2 - g0) * (g3 - g1);
    float iou = inter / (pa + ga - inter + EPSF);
    float sig = __builtin_amdgcn_rcpf(1.0f + __expf(-x));
    float i2 = iou * iou;
    return sig * (i2 * i2 * i2);
}

__device__ inline float fast_softplus(float x) {
    float e = __expf(-fabsf(x));
    return fmaxf(x, 0.0f) + __logf(1.0f + e);
}

// ---- block reduce helper (result valid on thread 0) ------------------------
__device__ inline float blockReduceSum(float v, float* sh) {
    for (int o = 32; o > 0; o >>= 1) v += __shfl_down(v, o, 64);
    int lane = threadIdx.x & 63;
    int w = threadIdx.x >> 6;
    __syncthreads();
    if (lane == 0) sh[w] = v;
    __syncthreads();
    float r = 0.0f;
    if (threadIdx.x == 0) r = sh[0] + sh[1] + sh[2] + sh[3];
    return r;
}

// ---- kernel 1: decode (1 thread per (branch,b,n,side)) + softplus stream ---
// Phase 1: 64B coalesced regs read, softmax-16, component-per-lane write.
// Phase 2: grid-stride softplus over BOTH cls tensors -> per-block partials.
// This is the designated bandwidth kernel (155 MB of the 155 MB compulsory).
__global__ __launch_bounds__(256) void decode_kernel(
    const float* __restrict__ regs0, const float* __restrict__ regs1,
    const float* __restrict__ cls0, const float* __restrict__ cls1,
    const float* __restrict__ anchors, const float* __restrict__ strides,
    float* __restrict__ pdbox, float* __restrict__ lse,
    float* __restrict__ psp)
{
    int tid = threadIdx.x;
    int i = blockIdx.x * 256 + tid;     // a*4 + s ; grid exactly covers range
    {
        int s = i & 3;
        int a = i >> 2;
        int br = a / (BB * NN);
        int bn = a - br * (BB * NN);
        int n = bn % NN;

        const float4* p4 = (const float4*)((br == 0 ? regs0 : regs1) + (size_t)bn * 64 + s * 16);
        float4 a0 = p4[0], a1 = p4[1], a2 = p4[2], a3 = p4[3];
        float xs[16] = {a0.x, a0.y, a0.z, a0.w, a1.x, a1.y, a1.z, a1.w,
                        a2.x, a2.y, a2.z, a2.w, a3.x, a3.y, a3.z, a3.w};
        float mx = xs[0];
#pragma unroll
        for (int j = 1; j < 16; ++j) mx = fmaxf(mx, xs[j]);
        float se = 0.0f, sd = 0.0f;
#pragma unroll
        for (int j = 0; j < 16; ++j) {
            float e = __expf(xs[j] - mx);
            se += e;
            sd += e * (float)j;
        }
        float d = sd * __builtin_amdgcn_rcpf(se);
        float l = mx + __logf(se);

        float anc = ((s & 1) == 0) ? anchors[2 * n] : anchors[2 * n + 1];
        float st = strides[n];
        pdbox[i] = (s < 2) ? (anc - d * st) : (anc + d * st);
        lse[i] = l;
    }

    // phase 2: softplus partial sums (independent of phase 1, no sync needed)
    const size_t half4 = (size_t)BB * NN * NCC / 4;   // float4 per branch
    float s0 = 0.0f, s1 = 0.0f;
    for (size_t idx = (size_t)blockIdx.x * 256 + tid; idx < 2 * half4;
         idx += (size_t)DBLOCKS * 256) {
        int br = (idx >= half4);
        float4 v = br ? ((const float4*)cls1)[idx - half4] : ((const float4*)cls0)[idx];
        float s = fast_softplus(v.x) + fast_softplus(v.y) +
                  fast_softplus(v.z) + fast_softplus(v.w);
        if (br) s1 += s; else s0 += s;
    }
    __shared__ float sh[4];
    float r0 = blockReduceSum(s0, sh);
    __syncthreads();
    float r1 = blockReduceSum(s1, sh);
    if (tid == 0) {
        psp[blockIdx.x * 2 + 0] = r0;
        psp[blockIdx.x * 2 + 1] = r1;
    }
}

// ---- kernel 2: fused align + top-k. One block per (branch,b,m) row. --------
// key = (float_bits(al) << 32) | (NN - n): al >= 0, so bigger key ==
// (greater value, then smaller index) — exact lax.top_k tie semantics.
__global__ __launch_bounds__(256) void align_topk_kernel(
    const float* __restrict__ cls0, const float* __restrict__ cls1,
    const float* __restrict__ anchors,
    const int* __restrict__ gt_labels, const float* __restrict__ gt_bboxes,
    const float* __restrict__ pdbox,
    int* __restrict__ topk1, int* __restrict__ topk2)
{
    int r = blockIdx.x;                 // 0 .. 2*BB*MM-1
    int br = r / (BB * MM);
    int bm = r - br * (BB * MM);
    int b = bm / MM;
    int tid = threadIdx.x;

    const float* gt = gt_bboxes + (size_t)bm * 4;
    float g0 = gt[0], g1 = gt[1], g2 = gt[2], g3 = gt[3];
    int lab = gt_labels[bm];
    const float* clscol = (br == 0 ? cls0 : cls1) + (size_t)b * NN * NCC + lab;
    const float4* pb4 = (const float4*)pdbox + (size_t)(br * BB + b) * NN;
    const float2* anc2 = (const float2*)anchors;

    if (br == 1) {
        // k = 1: packed-key max reduce
        unsigned long long best = 0ull;
        for (int n = tid; n < NN; n += 256) {
            float2 anc = anc2[n];
            unsigned long long key = (unsigned long long)(unsigned)(NN - n);
            if (anc.x >= g0 && anc.x <= g2 && anc.y >= g1 && anc.y <= g3) {
                float4 pb = pb4[n];
                float x = clscol[(size_t)n * NCC];
                float al = align_val(pb.x, pb.y, pb.z, pb.w, g0, g1, g2, g3, x);
                key |= ((unsigned long long)__float_as_uint(al) << 32);
            }
            if (key > best) best = key;
        }
        for (int o = 32; o > 0; o >>= 1) best = ullmax(best, __shfl_down(best, o, 64));
        __shared__ unsigned long long sm[4];
        int lane = tid & 63, w = tid >> 6;
        if (lane == 0) sm[w] = best;
        __syncthreads();
        if (tid == 0) {
            best = ullmax(ullmax(sm[0], sm[1]), ullmax(sm[2], sm[3]));
            topk2[bm] = NN - (int)(best & 0xffffffffull);
        }
        return;
    }

    // k = 10: branchless per-thread sorted top-10 (static indices, no spill),
    // then LDS tree merge.
    unsigned long long loc[10];
#pragma unroll
    for (int j = 0; j < 10; ++j) loc[j] = 0ull;
    for (int n = tid; n < NN; n += 256) {
        float2 anc = anc2[n];
        unsigned long long key = (unsigned long long)(unsigned)(NN - n);
        if (anc.x >= g0 && anc.x <= g2 && anc.y >= g1 && anc.y <= g3) {
            float4 pb = pb4[n];
            float x = clscol[(size_t)n * NCC];
            float al = align_val(pb.x, pb.y, pb.z, pb.w, g0, g1, g2, g3, x);
            key |= ((unsigned long long)__float_as_uint(al) << 32);
        }
        if (key > loc[9]) {
#pragma unroll
            for (int j = 9; j >= 1; --j)
                loc[j] = ullmax(loc[j], ullmin(loc[j - 1], key));
            loc[0] = ullmax(loc[0], key);
        }
    }

    __shared__ unsigned long long ls[256 * 10];
#pragma unroll
    for (int j = 0; j < 10; ++j) ls[tid * 10 + j] = loc[j];
    __syncthreads();

    for (int s = 128; s > 0; s >>= 1) {
        if (tid < s) {
            unsigned long long* A = &ls[tid * 10];
            unsigned long long* B2 = &ls[(tid + s) * 10];
            unsigned long long o[10];
            int ia = 0, ib = 0;
#pragma unroll
            for (int j = 0; j < 10; ++j) {
                unsigned long long av = A[ia], bv = B2[ib];
                if (av >= bv) { o[j] = av; ++ia; }
                else          { o[j] = bv; ++ib; }
            }
#pragma unroll
            for (int j = 0; j < 10; ++j) A[j] = o[j];
        }
        __syncthreads();
    }
    if (tid < 10) topk1[bm * 10 + tid] = NN - (int)(ls[tid] & 0xffffffffull);
}

// ---- kernel 3: assignment (column align recomputed) + fg-only losses -------
// grid: (NCHUNK, 2*BB); partial[(rb*NCHUNK+cx)*8+q], q: 0=sxt 1=box 2=dfl 3=nfg 4=mpos
__global__ __launch_bounds__(256) void assign_loss_kernel(
    const int* __restrict__ topk1, const int* __restrict__ topk2,
    const float* __restrict__ mask_gt,
    const int* __restrict__ gt_labels, const float* __restrict__ gt_bboxes,
    const float* __restrict__ cls0, const float* __restrict__ cls1,
    const float* __restrict__ regs0, const float* __restrict__ regs1,
    const float* __restrict__ anchors, const float* __restrict__ strides,
    const float* __restrict__ pdbox, const float* __restrict__ lse,
    float* __restrict__ partial)
{
    int cx = blockIdx.x;
    int rb = blockIdx.y;                 // branch*BB + b
    int br = rb / BB;
    int b = rb - br * BB;
    int tid = threadIdx.x;
    int n = cx * 256 + tid;

    __shared__ float g[MM * 4];
    __shared__ int gl[MM];
    __shared__ float gm[MM];
    __shared__ int tk[MM * 10];
    __shared__ int tk2s[MM];
    if (tid < MM * 4) g[tid] = gt_bboxes[b * MM * 4 + tid];
    if (tid < MM) {
        gl[tid] = gt_labels[b * MM + tid];
        gm[tid] = mask_gt[b * MM + tid];
        tk2s[tid] = topk2[b * MM + tid];
    }
    for (int j = tid; j < MM * 10; j += 256) tk[j] = topk1[b * MM * 10 + j];
    __syncthreads();

    const float* cls = (br == 0 ? cls0 : cls1);
    float sxt = 0.0f, sbox = 0.0f, sdfl = 0.0f, sfg = 0.0f, smp = 0.0f;

    if (n < NN) {
        const float* cp = cls + ((size_t)b * NN + n) * NCC;
        float2 anc = ((const float2*)anchors)[n];
        size_t i = (size_t)rb * NN + n;
        float4 pb = ((const float4*)pdbox)[i];

        // column argmax over m, align recomputed (bit-identical to topk's)
        float best = 0.0f;
        int mi = 0;
        for (int m = 0; m < MM; ++m) {
            float g0 = g[4 * m], g1 = g[4 * m + 1], g2 = g[4 * m + 2], g3 = g[4 * m + 3];
            if (anc.x >= g0 && anc.x <= g2 && anc.y >= g1 && anc.y <= g3) {
                float x = cp[gl[m]];
                float al = align_val(pb.x, pb.y, pb.z, pb.w, g0, g1, g2, g3, x);
                if (al > best) { best = al; mi = m; }
            }
        }

        int ind = 0;
        if (br == 0) {
            const int* tkp = &tk[mi * 10];
#pragma unroll
            for (int j = 0; j < 10; ++j)
                if (tkp[j] == n) ind = 1;
        } else {
            if (tk2s[mi] == n) ind = 1;
        }
        float mp = ind ? gm[mi] : 0.0f;
        smp = mp;
        if (mp > 0.0f) {
            sfg = 1.0f;
            float t0 = g[4 * mi] * mp, t1 = g[4 * mi + 1] * mp;
            float t2 = g[4 * mi + 2] * mp, t3 = g[4 * mi + 3] * mp;

            // plain IoU (for tscores)
            float iw = fmaxf(fminf(pb.z, t2) - fmaxf(pb.x, t0), 0.0f);
            float ih = fmaxf(fminf(pb.w, t3) - fmaxf(pb.y, t1), 0.0f);
            float inter = iw * ih;
            float w1 = pb.z - pb.x, h1 = pb.w - pb.y;
            float w2 = t2 - t0, h2 = t3 - t1;
            float uni = w1 * h1 + w2 * h2 - inter + EPSF;
            float iou = inter / uni;

            // -x*t term of BCE
            float x = cp[gl[mi]];
            sxt = x * iou;

            // CIoU (replicating reference's ch bug: ch = max(y2) - b1y1)
            float cw = fmaxf(pb.z, t2) - fminf(pb.x, t0);
            float ch = fmaxf(pb.w, t3) - pb.y;     // BUG in reference, replicated
            float c2 = cw * cw + ch * ch + EPSF;
            float dx = pb.x + pb.z - t0 - t2;
            float dy = pb.y + pb.w - t1 - t3;
            float rho2 = (dx * dx + dy * dy) * 0.25f;
            float dat = atanf(w2 / (h2 + EPSF)) - atanf(w1 / (h1 + EPSF));
            float v = 0.40528473f * dat * dat;     // 4/pi^2
            float alpha_ = v / (v - iou + 1.0000001f);
            float ciou = iou - (rho2 / c2 + v * alpha_);
            sbox = 1.0f - ciou;

            // DFL
            float st = strides[n];
            float tb[4] = {(anc.x - t0) / st, (anc.y - t1) / st,
                           (t2 - anc.x) / st, (t3 - anc.y) / st};
            float4 l4 = ((const float4*)lse)[i];
            float lv[4] = {l4.x, l4.y, l4.z, l4.w};
            const float* regs = (br == 0 ? regs0 : regs1) + ((size_t)b * NN + n) * 64;
            float dsum = 0.0f;
#pragma unroll
            for (int s2 = 0; s2 < 4; ++s2) {
                float t = fminf(fmaxf(tb[s2], 0.0f), (float)RMM - 1.01f);
                int tl = (int)t;
                float wl = (float)(tl + 1) - t;
                float wr = 1.0f - wl;
                float lp_l = regs[s2 * 16 + tl] - lv[s2];
                float lp_r = regs[s2 * 16 + tl + 1] - lv[s2];
                dsum += -(lp_l * wl + lp_r * wr);
            }
            sdfl = dsum;
        }
    }

    __shared__ float sh[4];
    float vals[5] = {sxt, sbox, sdfl, sfg, smp};
    float* outp = partial + ((size_t)rb * NCHUNK + cx) * 8;
#pragma unroll
    for (int q = 0; q < 5; ++q) {
        float r = blockReduceSum(vals[q], sh);
        if (tid == 0) outp[q] = r;
        __syncthreads();
    }
}

// ---- kernel 4: finalize (reduce all partials, emit 6 outputs) --------------
__global__ __launch_bounds__(256) void finalize_kernel(
    const float* __restrict__ partial, const float* __restrict__ psp,
    float* __restrict__ out)
{
    int tid = threadIdx.x;
    float s[10];
#pragma unroll
    for (int j = 0; j < 10; ++j) s[j] = 0.0f;
    const int nblk = 2 * BB * NCHUNK;
    for (int blk = tid; blk < nblk; blk += 256) {
        int br = blk / (BB * NCHUNK);
#pragma unroll
        for (int q = 0; q < 5; ++q) s[br * 5 + q] += partial[(size_t)blk * 8 + q];
    }
    float sp0 = 0.0f, sp1 = 0.0f;
    for (int i = tid; i < DBLOCKS; i += 256) {
        sp0 += psp[2 * i];
        sp1 += psp[2 * i + 1];
    }

    __shared__ float sh[4];
    __shared__ float res[12];
#pragma unroll
    for (int j = 0; j < 10; ++j) {
        float r = blockReduceSum(s[j], sh);
        if (tid == 0) res[j] = r;
        __syncthreads();
    }
    {
        float r = blockReduceSum(sp0, sh);
        if (tid == 0) res[10] = r;
        __syncthreads();
        r = blockReduceSum(sp1, sh);
        if (tid == 0) res[11] = r;
        __syncthreads();
    }

    if (tid == 0) {
        float t[2], c[2], bx[2], df[2];
        for (int br = 0; br < 2; ++br) {
            float a0 = res[br * 5 + 0], a1 = res[br * 5 + 1], a2 = res[br * 5 + 2];
            float a3 = res[br * 5 + 3], a4 = res[br * 5 + 4];
            float sp = res[10 + br];
            float nfg = fmaxf(a3, 1.0f);
            float lcls = (sp - a0) / fmaxf(a4, 1.0f);
            float lbox = a1 / nfg;
            float ldfl = a2 / (nfg * 4.0f);
            t[br] = lcls * 1.0f + lbox * 7.5f + ldfl * 1.5f;
            c[br] = lcls;
            bx[br] = lbox;
            df[br] = ldfl;
        }
        out[0] = t[0] + t[1];
        out[1] = c[0] + c[1];
        out[2] = bx[0] + bx[1];
        out[3] = df[0] + df[1];
        out[4] = t[0];
        out[5] = t[1];
    }
}

// ---------------------------------------------------------------------------
extern "C" void kernel_launch(void* const* d_in, const int* in_sizes, int n_in,
                              void* d_out, int out_size, void* d_ws, size_t ws_size,
                              hipStream_t stream) {
    const float* cls0    = (const float*)d_in[0];  // cls_scores
    const float* regs0   = (const float*)d_in[1];  // box_regs
    const float* cls1    = (const float*)d_in[2];  // one2one_cls
    const float* regs1   = (const float*)d_in[3];  // one2one_reg
    const float* anchors = (const float*)d_in[4];
    const float* strides = (const float*)d_in[5];
    const int*   gt_labels = (const int*)d_in[6];
    const float* gt_bboxes = (const float*)d_in[7];
    const float* mask_gt   = (const float*)d_in[8];
    float* out = (float*)d_out;

    float* pdbox   = (float*)d_ws;                       // 2*BB*NN*4
    float* lse     = pdbox + (size_t)2 * BB * NN * 4;    // 2*BB*NN*4
    int*   topk1   = (int*)(lse + (size_t)2 * BB * NN * 4);  // BB*MM*10
    int*   topk2   = topk1 + BB * MM * 10;               // BB*MM
    float* partial = (float*)(topk2 + BB * MM);          // 2*BB*NCHUNK*8
    float* psp     = partial + (size_t)2 * BB * NCHUNK * 8;  // DBLOCKS*2

    decode_kernel<<<DBLOCKS, 256, 0, stream>>>(
        regs0, regs1, cls0, cls1, anchors, strides, pdbox, lse, psp);

    align_topk_kernel<<<2 * BB * MM, 256, 0, stream>>>(
        cls0, cls1, anchors, gt_labels, gt_bboxes, pdbox, topk1, topk2);

    dim3 agrid(NCHUNK, 2 * BB);
    assign_loss_kernel<<<agrid, 256, 0, stream>>>(
        topk1, topk2, mask_gt, gt_labels, gt_bboxes,
        cls0, cls1, regs0, regs1, anchors, strides, pdbox, lse, partial);

    finalize_kernel<<<1, 256, 0, stream>>>(partial, psp, out);
}

// Round 7
// 220.755 us; speedup vs baseline: 2.5256x; 1.0448x over previous
//
#include <hip/hip_runtime.h>
#include <math.h>

#define BB 16
#define MM 32
#define NN 8400
#define NCC 80
#define RMM 16
#define EPSF 1e-7f
#define NCHUNK 33            // ceil(8400/256)
#define DBLOCKS 4200         // decode grid; phase1: 4 rounds exactly, phase2: 5 rounds

typedef unsigned long long ull;

// ---------------------------------------------------------------------------
// ws layout (floats):
//   pdbox   : 2*BB*NN*4   ([rb*NN+n][4])
//   lse     : 2*BB*NN*4
//   topk1   : BB*MM*10 (int)
//   topk2   : BB*MM    (int)
//   partial : 2*BB*NCHUNK*8   (assign_loss per-block partials, q0..q4)
//   psp     : DBLOCKS*2       (softplus per-block partials, from decode)
// ---------------------------------------------------------------------------

__device__ inline ull ullmax(ull a, ull b) { return a > b ? a : b; }
__device__ inline ull ullmin(ull a, ull b) { return a < b ? a : b; }

// Shared align-metric computation. __noinline__ => ONE codegen => bit-identical
// values in align_topk_kernel and assign_loss_kernel (assign's argmax must
// agree with topk's ordering on the same logical values).
__device__ __noinline__ float align_val(
    float px, float py, float pz, float pw,
    float g0, float g1, float g2, float g3, float x)
{
    float iw = fmaxf(fminf(pz, g2) - fmaxf(px, g0), 0.0f);
    float ih = fmaxf(fminf(pw, g3) - fmaxf(py, g1), 0.0f);
    float inter = iw * ih;
    float pa = (pz - px) * (pw - py);
    float ga = (g2 - g0) * (g3 - g1);
    float iou = inter / (pa + ga - inter + EPSF);
    float sig = __builtin_amdgcn_rcpf(1.0f + __expf(-x));
    float i2 = iou * iou;
    return sig * (i2 * i2 * i2);
}

__device__ inline float fast_softplus(float x) {
    float e = __expf(-fabsf(x));
    return fmaxf(x, 0.0f) + __logf(1.0f + e);
}

// ---- block reduce helper (result valid on thread 0) ------------------------
__device__ inline float blockReduceSum(float v, float* sh) {
    for (int o = 32; o > 0; o >>= 1) v += __shfl_down(v, o, 64);
    int lane = threadIdx.x & 63;
    int w = threadIdx.x >> 6;
    __syncthreads();
    if (lane == 0) sh[w] = v;
    __syncthreads();
    float r = 0.0f;
    if (threadIdx.x == 0) r = sh[0] + sh[1] + sh[2] + sh[3];
    return r;
}

// ---- kernel 1: decode (quad-cooperative softmax) + softplus stream ---------
// Phase 1: 4 lanes per side; each lane loads ONE contiguous float4 (waves read
// contiguous 1KB per load instr — fixes the 64B-stride 4x cache-line tax).
// Phase 2: grid-stride softplus over both cls tensors.
__global__ __launch_bounds__(256) void decode_kernel(
    const float* __restrict__ regs0, const float* __restrict__ regs1,
    const float* __restrict__ cls0, const float* __restrict__ cls1,
    const float* __restrict__ anchors, const float* __restrict__ strides,
    float* __restrict__ pdbox, float* __restrict__ lse,
    float* __restrict__ psp)
{
    int tid = threadIdx.x;
    int lane = tid & 63;
    const size_t QSTR = (size_t)DBLOCKS * 256;      // 1,075,200 threads
    const size_t QPB  = (size_t)BB * NN * 16;       // quarters per branch = 2,150,400
    size_t base = (size_t)blockIdx.x * 256 + tid;

#pragma unroll
    for (int r = 0; r < 4; ++r) {
        size_t Q = base + (size_t)r * QSTR;         // global quarter index
        int br = Q >= QPB;
        const float4* src = (const float4*)(br ? regs1 : regs0);
        float4 v = src[Q - (br ? QPB : 0)];         // fully coalesced

        float mx = fmaxf(fmaxf(v.x, v.y), fmaxf(v.z, v.w));
        mx = fmaxf(mx, __shfl_xor(mx, 1, 4));
        mx = fmaxf(mx, __shfl_xor(mx, 2, 4));

        int q = lane & 3;
        float w0 = (float)(q * 4);
        float e0 = __expf(v.x - mx), e1 = __expf(v.y - mx);
        float e2 = __expf(v.z - mx), e3 = __expf(v.w - mx);
        float se = e0 + e1 + e2 + e3;
        float sd = e0 * w0 + e1 * (w0 + 1.0f) + e2 * (w0 + 2.0f) + e3 * (w0 + 3.0f);
        se += __shfl_xor(se, 1, 4); se += __shfl_xor(se, 2, 4);
        sd += __shfl_xor(sd, 1, 4); sd += __shfl_xor(sd, 2, 4);

        float d = sd * __builtin_amdgcn_rcpf(se);
        float l = mx + __logf(se);

        // gather the 4 sides' (d,l) to the anchor's writer lane (lane%16==0)
        int gb = lane & ~15;
        float d0 = __shfl(d, gb + 0),  d1 = __shfl(d, gb + 4);
        float d2 = __shfl(d, gb + 8),  d3 = __shfl(d, gb + 12);
        float l0 = __shfl(l, gb + 0),  l1 = __shfl(l, gb + 4);
        float l2 = __shfl(l, gb + 8),  l3 = __shfl(l, gb + 12);

        if ((lane & 15) == 0) {
            int A = (int)(Q >> 4);                  // global anchor index
            int bn = A - br * (BB * NN);
            int n = bn % NN;
            float ax = anchors[2 * n], ay = anchors[2 * n + 1];
            float st = strides[n];
            ((float4*)pdbox)[A] = make_float4(ax - d0 * st, ay - d1 * st,
                                              ax + d2 * st, ay + d3 * st);
            ((float4*)lse)[A] = make_float4(l0, l1, l2, l3);
        }
    }

    // phase 2: softplus partial sums over both cls tensors (5 rounds exactly)
    const size_t half4 = (size_t)BB * NN * NCC / 4;   // 2,688,000 float4 per branch
    float s0 = 0.0f, s1 = 0.0f;
    for (size_t idx = base; idx < 2 * half4; idx += QSTR) {
        int br = (idx >= half4);
        float4 v = br ? ((const float4*)cls1)[idx - half4] : ((const float4*)cls0)[idx];
        float s = fast_softplus(v.x) + fast_softplus(v.y) +
                  fast_softplus(v.z) + fast_softplus(v.w);
        if (br) s1 += s; else s0 += s;
    }
    __shared__ float sh[4];
    float r0 = blockReduceSum(s0, sh);
    __syncthreads();
    float r1 = blockReduceSum(s1, sh);
    if (tid == 0) {
        psp[blockIdx.x * 2 + 0] = r0;
        psp[blockIdx.x * 2 + 1] = r1;
    }
}

// ---- kernel 2: align + top-k via analytic in-box rectangle enumeration ----
// In-box anchors of gt [g0,g1,g2,g3] form a rectangle per anchor level
// (stride 8/16/32, grid 80/40/20). Enumerate rectangle candidates (widened
// +-1, re-tested with the EXACT reference float compares) plus candidates
// n=0..63 (reproduces lax.top_k zero-padding tie semantics; padding indices
// are provably within 0..63 since padding only occurs when <10 positives
// exist, leaving >=54 zero-align indices among 0..63). Rectangles skip n<64
// to avoid duplicates. key = (bits(al)<<32)|(NN-n): desc value, asc index.
__global__ __launch_bounds__(256) void align_topk_kernel(
    const float* __restrict__ cls0, const float* __restrict__ cls1,
    const int* __restrict__ gt_labels, const float* __restrict__ gt_bboxes,
    const float* __restrict__ pdbox,
    int* __restrict__ topk1, int* __restrict__ topk2)
{
    int r = blockIdx.x;                 // 0 .. 2*BB*MM-1
    int br = r / (BB * MM);
    int bm = r - br * (BB * MM);
    int b = bm / MM;
    int tid = threadIdx.x;

    const float* gt = gt_bboxes + (size_t)bm * 4;
    float g0 = gt[0], g1 = gt[1], g2 = gt[2], g3 = gt[3];
    int lab = gt_labels[bm];
    const float* clscol = (br == 0 ? cls0 : cls1) + (size_t)b * NN * NCC + lab;
    const float4* pb4 = (const float4*)pdbox + (size_t)(br * BB + b) * NN;

    const int lvl_s[3] = {8, 16, 32};
    const int lvl_g[3] = {80, 40, 20};
    const int lvl_b[3] = {0, 6400, 8000};

    // --- per-thread candidate scan -> sorted top-10 (branchless insert) ---
    ull loc[10];
#pragma unroll
    for (int j = 0; j < 10; ++j) loc[j] = 0ull;

    // fixed candidates n = 0..63 (level 0, gy=0, gx=n)
    if (tid < 64) {
        int n = tid;
        float ax = ((float)n + 0.5f) * 8.0f, ay = 4.0f;
        ull key = (ull)(unsigned)(NN - n);
        if (ax >= g0 && ax <= g2 && ay >= g1 && ay <= g3) {
            float4 pb = pb4[n];
            float x = clscol[(size_t)n * NCC];
            float al = align_val(pb.x, pb.y, pb.z, pb.w, g0, g1, g2, g3, x);
            key |= ((ull)__float_as_uint(al) << 32);
        }
#pragma unroll
        for (int j = 9; j >= 1; --j)
            loc[j] = ullmax(loc[j], ullmin(loc[j - 1], key));
        loc[0] = ullmax(loc[0], key);
    }

    // rectangle candidates per level
    for (int lvl = 0; lvl < 3; ++lvl) {
        int s = lvl_s[lvl], g = lvl_g[lvl], nb = lvl_b[lvl];
        float fs = (float)s;
        int x0 = (int)ceilf(g0 / fs - 0.5f) - 1; if (x0 < 0) x0 = 0;
        int x1 = (int)floorf(g2 / fs - 0.5f) + 1; if (x1 > g - 1) x1 = g - 1;
        int y0 = (int)ceilf(g1 / fs - 0.5f) - 1; if (y0 < 0) y0 = 0;
        int y1 = (int)floorf(g3 / fs - 0.5f) + 1; if (y1 > g - 1) y1 = g - 1;
        int rw = x1 - x0 + 1, rh = y1 - y0 + 1;
        if (rw <= 0 || rh <= 0) continue;
        int cnt = rw * rh;
        for (int c = tid; c < cnt; c += 256) {
            int gy = y0 + c / rw;
            int gx = x0 + c % rw;
            int n = nb + gy * g + gx;
            if (n < 64) continue;       // covered by fixed set
            float ax = ((float)gx + 0.5f) * fs;
            float ay = ((float)gy + 0.5f) * fs;
            if (!(ax >= g0 && ax <= g2 && ay >= g1 && ay <= g3)) continue;
            float4 pb = pb4[n];
            float x = clscol[(size_t)n * NCC];
            float al = align_val(pb.x, pb.y, pb.z, pb.w, g0, g1, g2, g3, x);
            ull key = ((ull)__float_as_uint(al) << 32) | (unsigned)(NN - n);
            if (key > loc[9]) {
#pragma unroll
                for (int j = 9; j >= 1; --j)
                    loc[j] = ullmax(loc[j], ullmin(loc[j - 1], key));
                loc[0] = ullmax(loc[0], key);
            }
        }
    }

    if (br == 1) {
        // k = 1: max-reduce of loc[0]
        ull best = loc[0];
        for (int o = 32; o > 0; o >>= 1) best = ullmax(best, __shfl_down(best, o, 64));
        __shared__ ull sm[4];
        int lane = tid & 63, w = tid >> 6;
        if (lane == 0) sm[w] = best;
        __syncthreads();
        if (tid == 0) {
            best = ullmax(ullmax(sm[0], sm[1]), ullmax(sm[2], sm[3]));
            topk2[bm] = NN - (int)(best & 0xffffffffull);
        }
        return;
    }

    // k = 10: LDS tree merge of sorted lists
    __shared__ ull ls[256 * 10];
#pragma unroll
    for (int j = 0; j < 10; ++j) ls[tid * 10 + j] = loc[j];
    __syncthreads();

    for (int s = 128; s > 0; s >>= 1) {
        if (tid < s) {
            ull* A = &ls[tid * 10];
            ull* B2 = &ls[(tid + s) * 10];
            ull o[10];
            int ia = 0, ib = 0;
#pragma unroll
            for (int j = 0; j < 10; ++j) {
                ull av = A[ia], bv = B2[ib];
                if (av >= bv) { o[j] = av; ++ia; }
                else          { o[j] = bv; ++ib; }
            }
#pragma unroll
            for (int j = 0; j < 10; ++j) A[j] = o[j];
        }
        __syncthreads();
    }
    if (tid < 10) topk1[bm * 10 + tid] = NN - (int)(ls[tid] & 0xffffffffull);
}

// ---- kernel 3: assignment (column align recomputed) + fg-only losses -------
// grid: (NCHUNK, 2*BB); partial[(rb*NCHUNK+cx)*8+q], q: 0=sxt 1=box 2=dfl 3=nfg 4=mpos
__global__ __launch_bounds__(256) void assign_loss_kernel(
    const int* __restrict__ topk1, const int* __restrict__ topk2,
    const float* __restrict__ mask_gt,
    const int* __restrict__ gt_labels, const float* __restrict__ gt_bboxes,
    const float* __restrict__ cls0, const float* __restrict__ cls1,
    const float* __restrict__ regs0, const float* __restrict__ regs1,
    const float* __restrict__ anchors, const float* __restrict__ strides,
    const float* __restrict__ pdbox, const float* __restrict__ lse,
    float* __restrict__ partial)
{
    int cx = blockIdx.x;
    int rb = blockIdx.y;                 // branch*BB + b
    int br = rb / BB;
    int b = rb - br * BB;
    int tid = threadIdx.x;
    int n = cx * 256 + tid;

    __shared__ float g[MM * 4];
    __shared__ int gl[MM];
    __shared__ float gm[MM];
    __shared__ int tk[MM * 10];
    __shared__ int tk2s[MM];
    if (tid < MM * 4) g[tid] = gt_bboxes[b * MM * 4 + tid];
    if (tid < MM) {
        gl[tid] = gt_labels[b * MM + tid];
        gm[tid] = mask_gt[b * MM + tid];
        tk2s[tid] = topk2[b * MM + tid];
    }
    for (int j = tid; j < MM * 10; j += 256) tk[j] = topk1[b * MM * 10 + j];
    __syncthreads();

    const float* cls = (br == 0 ? cls0 : cls1);
    float sxt = 0.0f, sbox = 0.0f, sdfl = 0.0f, sfg = 0.0f, smp = 0.0f;

    if (n < NN) {
        const float* cp = cls + ((size_t)b * NN + n) * NCC;
        float2 anc = ((const float2*)anchors)[n];
        size_t i = (size_t)rb * NN + n;
        float4 pb = ((const float4*)pdbox)[i];

        // column argmax over m, align recomputed (bit-identical to topk's)
        float best = 0.0f;
        int mi = 0;
        for (int m = 0; m < MM; ++m) {
            float g0 = g[4 * m], g1 = g[4 * m + 1], g2 = g[4 * m + 2], g3 = g[4 * m + 3];
            if (anc.x >= g0 && anc.x <= g2 && anc.y >= g1 && anc.y <= g3) {
                float x = cp[gl[m]];
                float al = align_val(pb.x, pb.y, pb.z, pb.w, g0, g1, g2, g3, x);
                if (al > best) { best = al; mi = m; }
            }
        }

        int ind = 0;
        if (br == 0) {
            const int* tkp = &tk[mi * 10];
#pragma unroll
            for (int j = 0; j < 10; ++j)
                if (tkp[j] == n) ind = 1;
        } else {
            if (tk2s[mi] == n) ind = 1;
        }
        float mp = ind ? gm[mi] : 0.0f;
        smp = mp;
        if (mp > 0.0f) {
            sfg = 1.0f;
            float t0 = g[4 * mi] * mp, t1 = g[4 * mi + 1] * mp;
            float t2 = g[4 * mi + 2] * mp, t3 = g[4 * mi + 3] * mp;

            // plain IoU (for tscores)
            float iw = fmaxf(fminf(pb.z, t2) - fmaxf(pb.x, t0), 0.0f);
            float ih = fmaxf(fminf(pb.w, t3) - fmaxf(pb.y, t1), 0.0f);
            float inter = iw * ih;
            float w1 = pb.z - pb.x, h1 = pb.w - pb.y;
            float w2 = t2 - t0, h2 = t3 - t1;
            float uni = w1 * h1 + w2 * h2 - inter + EPSF;
            float iou = inter / uni;

            // -x*t term of BCE
            float x = cp[gl[mi]];
            sxt = x * iou;

            // CIoU (replicating reference's ch bug: ch = max(y2) - b1y1)
            float cw = fmaxf(pb.z, t2) - fminf(pb.x, t0);
            float ch = fmaxf(pb.w, t3) - pb.y;     // BUG in reference, replicated
            float c2 = cw * cw + ch * ch + EPSF;
            float dx = pb.x + pb.z - t0 - t2;
            float dy = pb.y + pb.w - t1 - t3;
            float rho2 = (dx * dx + dy * dy) * 0.25f;
            float dat = atanf(w2 / (h2 + EPSF)) - atanf(w1 / (h1 + EPSF));
            float v = 0.40528473f * dat * dat;     // 4/pi^2
            float alpha_ = v / (v - iou + 1.0000001f);
            float ciou = iou - (rho2 / c2 + v * alpha_);
            sbox = 1.0f - ciou;

            // DFL
            float st = strides[n];
            float tb[4] = {(anc.x - t0) / st, (anc.y - t1) / st,
                           (t2 - anc.x) / st, (t3 - anc.y) / st};
            float4 l4 = ((const float4*)lse)[i];
            float lv[4] = {l4.x, l4.y, l4.z, l4.w};
            const float* regs = (br == 0 ? regs0 : regs1) + ((size_t)b * NN + n) * 64;
            float dsum = 0.0f;
#pragma unroll
            for (int s2 = 0; s2 < 4; ++s2) {
                float t = fminf(fmaxf(tb[s2], 0.0f), (float)RMM - 1.01f);
                int tl = (int)t;
                float wl = (float)(tl + 1) - t;
                float wr = 1.0f - wl;
                float lp_l = regs[s2 * 16 + tl] - lv[s2];
                float lp_r = regs[s2 * 16 + tl + 1] - lv[s2];
                dsum += -(lp_l * wl + lp_r * wr);
            }
            sdfl = dsum;
        }
    }

    __shared__ float sh[4];
    float vals[5] = {sxt, sbox, sdfl, sfg, smp};
    float* outp = partial + ((size_t)rb * NCHUNK + cx) * 8;
#pragma unroll
    for (int q = 0; q < 5; ++q) {
        float r = blockReduceSum(vals[q], sh);
        if (tid == 0) outp[q] = r;
        __syncthreads();
    }
}

// ---- kernel 4: finalize (reduce all partials, emit 6 outputs) --------------
__global__ __launch_bounds__(256) void finalize_kernel(
    const float* __restrict__ partial, const float* __restrict__ psp,
    float* __restrict__ out)
{
    int tid = threadIdx.x;
    float s[10];
#pragma unroll
    for (int j = 0; j < 10; ++j) s[j] = 0.0f;
    const int nblk = 2 * BB * NCHUNK;
    for (int blk = tid; blk < nblk; blk += 256) {
        int br = blk / (BB * NCHUNK);
#pragma unroll
        for (int q = 0; q < 5; ++q) s[br * 5 + q] += partial[(size_t)blk * 8 + q];
    }
    float sp0 = 0.0f, sp1 = 0.0f;
    for (int i = tid; i < DBLOCKS; i += 256) {
        sp0 += psp[2 * i];
        sp1 += psp[2 * i + 1];
    }

    __shared__ float sh[4];
    __shared__ float res[12];
#pragma unroll
    for (int j = 0; j < 10; ++j) {
        float r = blockReduceSum(s[j], sh);
        if (tid == 0) res[j] = r;
        __syncthreads();
    }
    {
        float r = blockReduceSum(sp0, sh);
        if (tid == 0) res[10] = r;
        __syncthreads();
        r = blockReduceSum(sp1, sh);
        if (tid == 0) res[11] = r;
        __syncthreads();
    }

    if (tid == 0) {
        float t[2], c[2], bx[2], df[2];
        for (int br = 0; br < 2; ++br) {
            float a0 = res[br * 5 + 0], a1 = res[br * 5 + 1], a2 = res[br * 5 + 2];
            float a3 = res[br * 5 + 3], a4 = res[br * 5 + 4];
            float sp = res[10 + br];
            float nfg = fmaxf(a3, 1.0f);
            float lcls = (sp - a0) / fmaxf(a4, 1.0f);
            float lbox = a1 / nfg;
            float ldfl = a2 / (nfg * 4.0f);
            t[br] = lcls * 1.0f + lbox * 7.5f + ldfl * 1.5f;
            c[br] = lcls;
            bx[br] = lbox;
            df[br] = ldfl;
        }
        out[0] = t[0] + t[1];
        out[1] = c[0] + c[1];
        out[2] = bx[0] + bx[1];
        out[3] = df[0] + df[1];
        out[4] = t[0];
        out[5] = t[1];
    }
}

// ---------------------------------------------------------------------------
extern "C" void kernel_launch(void* const* d_in, const int* in_sizes, int n_in,
                              void* d_out, int out_size, void* d_ws, size_t ws_size,
                              hipStream_t stream) {
    const float* cls0    = (const float*)d_in[0];  // cls_scores
    const float* regs0   = (const float*)d_in[1];  // box_regs
    const float* cls1    = (const float*)d_in[2];  // one2one_cls
    const float* regs1   = (const float*)d_in[3];  // one2one_reg
    const float* anchors = (const float*)d_in[4];
    const float* strides = (const float*)d_in[5];
    const int*   gt_labels = (const int*)d_in[6];
    const float* gt_bboxes = (const float*)d_in[7];
    const float* mask_gt   = (const float*)d_in[8];
    float* out = (float*)d_out;

    float* pdbox   = (float*)d_ws;                       // 2*BB*NN*4
    float* lse     = pdbox + (size_t)2 * BB * NN * 4;    // 2*BB*NN*4
    int*   topk1   = (int*)(lse + (size_t)2 * BB * NN * 4);  // BB*MM*10
    int*   topk2   = topk1 + BB * MM * 10;               // BB*MM
    float* partial = (float*)(topk2 + BB * MM);          // 2*BB*NCHUNK*8
    float* psp     = partial + (size_t)2 * BB * NCHUNK * 8;  // DBLOCKS*2

    decode_kernel<<<DBLOCKS, 256, 0, stream>>>(
        regs0, regs1, cls0, cls1, anchors, strides, pdbox, lse, psp);

    align_topk_kernel<<<2 * BB * MM, 256, 0, stream>>>(
        cls0, cls1, gt_labels, gt_bboxes, pdbox, topk1, topk2);

    dim3 agrid(NCHUNK, 2 * BB);
    assign_loss_kernel<<<agrid, 256, 0, stream>>>(
        topk1, topk2, mask_gt, gt_labels, gt_bboxes,
        cls0, cls1, regs0, regs1, anchors, strides, pdbox, lse, partial);

    finalize_kernel<<<1, 256, 0, stream>>>(partial, psp, out);
}